// Round 5
// baseline (17090.544 us; speedup 1.0000x reference)
//
#include <hip/hip_runtime.h>
#include <hip/hip_fp16.h>
#include <stdint.h>

#define BB 128
#define SS 256
#define HH 512
#define QQ 360
#define QP 368   // padded Q (16 subsets * 23), pad rows zeroed

// ---------------- Threefry-2x32 (JAX semantics) ----------------
struct TF2 { uint32_t a, b; };

__host__ __device__ constexpr uint32_t rotl32(uint32_t x, int d) {
  return (x << d) | (x >> (32 - d));
}

__host__ __device__ constexpr TF2 threefry(uint32_t k0, uint32_t k1,
                                           uint32_t x0, uint32_t x1) {
  uint32_t ks[3] = {k0, k1, k0 ^ k1 ^ 0x1BD11BDAu};
  x0 += ks[0]; x1 += ks[1];
  const int R0[4] = {13, 15, 26, 6};
  const int R1[4] = {17, 29, 16, 24};
  for (int g = 0; g < 5; ++g) {
    const int* r = (g & 1) ? R1 : R0;
    for (int i = 0; i < 4; ++i) { x0 += x1; x1 = rotl32(x1, r[i]); x1 ^= x0; }
    x0 += ks[(g + 1) % 3];
    x1 += ks[(g + 2) % 3] + (uint32_t)(g + 1);
  }
  return TF2{x0, x1};
}

struct KeyTab { uint32_t sk[256][2]; };
constexpr KeyTab make_keys() {
  KeyTab K{};
  uint32_t k0 = 0u, k1 = 1u;
  for (int t = 0; t < 256; ++t) {
    TF2 nk = threefry(k0, k1, 0u, 0u);
    TF2 sk = threefry(k0, k1, 0u, 1u);
    K.sk[t][0] = sk.a; K.sk[t][1] = sk.b;
    k0 = nk.a; k1 = nk.b;
  }
  return K;
}
__constant__ KeyTab c_keys = make_keys();

// ---------------- fast math helpers ----------------
__device__ __forceinline__ float frcp(float x) {
#if __has_builtin(__builtin_amdgcn_rcpf)
  return __builtin_amdgcn_rcpf(x);
#else
  return 1.0f / x;
#endif
}

#if __has_builtin(__builtin_amdgcn_exp2f)
  #define EXP2F(x) __builtin_amdgcn_exp2f(x)
  #define CC 2.8853900817779268f
#else
  #define EXP2F(x) __expf(x)
  #define CC 2.0f
#endif

#define ENC_SCALE 21.0f
#define ENC_INV (CC / ENC_SCALE)

__device__ __forceinline__ float fast_tanh(float x) {
  float e = __expf(2.0f * x);
  return 1.0f - 2.0f * frcp(e + 1.0f);
}

// ---------------- Phase A1: enc8[b][h][s] = int8( 21 * (inputs @ Wc + bc)^T ) ----------------
__global__ __launch_bounds__(256) void k_enc(const float* __restrict__ inputs,
                                             const float* __restrict__ Wc,
                                             const float* __restrict__ bc,
                                             int8_t* __restrict__ enc8) {
  const int ht = blockIdx.x;
  const int b  = blockIdx.y;
  const int tid = threadIdx.x;
  const int ts = tid & 63, th = tid >> 6;
  __shared__ float Xs[32 * 260];
  __shared__ float Ws[32 * 64];
  float acc[16][4];
#pragma unroll
  for (int i = 0; i < 16; ++i)
#pragma unroll
    for (int j = 0; j < 4; ++j) acc[i][j] = 0.f;

  const float* Arow = inputs + ((size_t)b * SS + tid) * HH;
  for (int kk = 0; kk < HH; kk += 32) {
    const float4* ip = (const float4*)(Arow + kk);
#pragma unroll
    for (int e = 0; e < 8; ++e) {
      float4 w = ip[e];
      Xs[(e * 4 + 0) * 260 + tid] = w.x;
      Xs[(e * 4 + 1) * 260 + tid] = w.y;
      Xs[(e * 4 + 2) * 260 + tid] = w.z;
      Xs[(e * 4 + 3) * 260 + tid] = w.w;
    }
    {
      int kw = tid >> 3, hw = (tid & 7) * 8;
      const float4* wp = (const float4*)(Wc + (size_t)(kk + kw) * HH + ht * 64 + hw);
      float4 w0 = wp[0], w1 = wp[1];
      float* d = Ws + kw * 64 + hw;
      ((float4*)d)[0] = w0; ((float4*)d)[1] = w1;
    }
    __syncthreads();
#pragma unroll 8
    for (int k = 0; k < 32; ++k) {
      float xr[4];
#pragma unroll
      for (int j = 0; j < 4; ++j) xr[j] = Xs[k * 260 + ts + 64 * j];
      const float4* wr4 = (const float4*)(Ws + k * 64 + th * 16);
#pragma unroll
      for (int i4 = 0; i4 < 4; ++i4) {
        float4 w = wr4[i4];
        float wv[4] = {w.x, w.y, w.z, w.w};
#pragma unroll
        for (int c = 0; c < 4; ++c)
#pragma unroll
          for (int j = 0; j < 4; ++j) acc[i4 * 4 + c][j] += wv[c] * xr[j];
      }
    }
    __syncthreads();
  }
#pragma unroll
  for (int i = 0; i < 16; ++i) {
    int h = ht * 64 + th * 16 + i;
    float bcv = bc[h];
    int8_t* orow = enc8 + (size_t)b * (HH * SS) + (size_t)h * SS + ts;
#pragma unroll
    for (int j = 0; j < 4; ++j) {
      float q = rintf(fminf(fmaxf((acc[i][j] + bcv) * ENC_SCALE, -127.f), 127.f));
      orow[64 * j] = (int8_t)(int)q;
    }
  }
}

// ---------------- Phase A2: G[b][j][k][q] = half( inputs[b,j,:] @ Wq[k] ) ----------------
__global__ __launch_bounds__(256) void k_G(const float* __restrict__ inputs,
                                           const float* __restrict__ Wq,
                                           __half* __restrict__ G) {
  const int qt = blockIdx.x;
  const int b  = blockIdx.y;
  const int k  = blockIdx.z;
  const int tid = threadIdx.x;
  const int ql = tid & 63, tj = tid >> 6;
  __shared__ float Xs[32 * 260];
  __shared__ float Ws[32 * 64];
  float acc[64];
#pragma unroll
  for (int j = 0; j < 64; ++j) acc[j] = 0.f;
  const int q = qt * 64 + ql;
  const float* Arow = inputs + ((size_t)b * SS + tid) * HH;
  const float* Wqk = Wq + (size_t)k * HH * QQ;
  for (int kk = 0; kk < HH; kk += 32) {
    const float4* ip = (const float4*)(Arow + kk);
#pragma unroll
    for (int e = 0; e < 8; ++e) {
      float4 w = ip[e];
      Xs[(e * 4 + 0) * 260 + tid] = w.x;
      Xs[(e * 4 + 1) * 260 + tid] = w.y;
      Xs[(e * 4 + 2) * 260 + tid] = w.z;
      Xs[(e * 4 + 3) * 260 + tid] = w.w;
    }
    {
      int hh = tid >> 3, qw = (tid & 7) * 8;
      const float* src = Wqk + (size_t)(kk + hh) * QQ;
      float* d = Ws + hh * 64 + qw;
#pragma unroll
      for (int e = 0; e < 8; ++e) {
        int qg = qt * 64 + qw + e;
        d[e] = (qg < QQ) ? src[qg] : 0.f;
      }
    }
    __syncthreads();
#pragma unroll 4
    for (int k2 = 0; k2 < 32; ++k2) {
      float wr = Ws[k2 * 64 + ql];
      const float4* xp = (const float4*)(Xs + k2 * 260 + tj * 64);
#pragma unroll
      for (int j4 = 0; j4 < 16; ++j4) {
        float4 x = xp[j4];
        acc[j4 * 4 + 0] += wr * x.x;
        acc[j4 * 4 + 1] += wr * x.y;
        acc[j4 * 4 + 2] += wr * x.z;
        acc[j4 * 4 + 3] += wr * x.w;
      }
    }
    __syncthreads();
  }
  if (q < QQ) {
#pragma unroll
    for (int j = 0; j < 64; ++j) {
      size_t jg = (size_t)b * SS + (tj * 64 + j);
      G[(jg * 3 + k) * QQ + q] = __float2half(acc[j]);
    }
  }
}

// ---------------- w_q fp32 -> fp16, padded to QP rows (pad = 0) ----------------
__global__ __launch_bounds__(1024) void k_wq16(const float* __restrict__ w_q,
                                               __half* __restrict__ w16) {
  int t = blockIdx.x * 1024 + threadIdx.x;
  if (t < QP * HH) w16[t] = (t < QQ * HH) ? __float2half(w_q[t]) : __half(0);
}

// ---------------- Main scan ----------------
// Latency-restructured:
//  - Gumbel/threefry + mask read hoisted before b1 (depends only on t), all waves.
//  - P4 spread over all 16 waves: 4 threads per s, each sums 4 part rows.
//  - P2 widened to dwordx4 w16 loads: 16 q-subsets x 4 h-groups of 8 h.
__global__ __launch_bounds__(1024, 4) void k_scan(
    const __half* __restrict__ w16, const float* __restrict__ v,
    const int8_t* __restrict__ enc8, const __half* __restrict__ G,
    float* __restrict__ out, double* __restrict__ lpb, double* __restrict__ entb) {
  const int b = blockIdx.x;
  const int tid = (int)threadIdx.x;
  const int lane = tid & 63;
  const int wid = tid >> 6;            // 16 waves
  // P2 geometry: lane = q_sub*4 + hq; q_sub 0..15 (23 q each), hq 0..3 (8 h each)
  const int q_sub = lane >> 2;
  const int hq = lane & 3;
  // P3 geometry
  const int hl = lane >> 5;            // 0..1
  const int sl = lane & 31;
  const int sbase = sl * 8;
  // P4 geometry: 4 threads per s
  const int s4 = tid >> 2;             // 0..255
  const int rq = tid & 3;              // 0..3

  __shared__ float2 evq[HH];           // .x = exp2(CC*eq[h]) (per step), .y = -2*v[h]
  __shared__ float q_s[QP];            // current query (relu'd), pad zeroed
  __shared__ float q12_s[QP];          // prefetched G0+G1 for next step
  __shared__ float part[16][SS];
  __shared__ float m_s[SS];
  __shared__ float mask_s[SS];
  __shared__ float4 wred[16];
  __shared__ int hist[3];
  __shared__ float Vtot_s;

  // ---- init ----
  if (tid < HH) evq[tid] = make_float2(1.0f, -2.0f * v[tid]);  // F=exp2(0)=1
  if (tid < SS) mask_s[tid] = 0.f;
  if (tid < QP) { q_s[tid] = 0.f; q12_s[tid] = 0.f; }
  if (tid < 3) hist[tid] = -1;
  if (tid < 64) {
    float s = 0.f;
#pragma unroll
    for (int j = 0; j < 8; ++j) s += v[tid + 64 * j];
#pragma unroll
    for (int off = 32; off; off >>= 1) s += __shfl_xor(s, off);
    if (tid == 0) Vtot_s = s;
  }
  __syncthreads();
  const float Vtot = Vtot_s;

  // ---- register-resident E = exp2(ENC_INV * enc8), packed bf16 pairs ----
  uint32_t E_r[64];
  {
    const int8_t* encW = enc8 + (size_t)b * (HH * SS) + (size_t)(wid * 32 + hl) * SS + sbase;
#pragma unroll
    for (int i = 0; i < 16; ++i) {
      uint2 w = *(const uint2*)(encW + (size_t)(2 * i) * SS);
#pragma unroll
      for (int p = 0; p < 2; ++p) {
        uint32_t wb = p ? w.y : w.x;
#pragma unroll
        for (int kp = 0; kp < 2; ++kp) {
          float f0 = (float)(int)(int8_t)(wb >> (16 * kp));
          float f1 = (float)(int)(int8_t)(wb >> (16 * kp + 8));
          float e0 = EXP2F(f0 * ENC_INV);
          float e1 = EXP2F(f1 * ENC_INV);
          uint32_t b0 = (__float_as_uint(e0) + 0x8000u) >> 16;
          uint32_t b1 = (__float_as_uint(e1) + 0x8000u) & 0xFFFF0000u;
          E_r[i * 4 + p * 2 + kp] = b0 | b1;
        }
      }
    }
  }

  const __half* Gb = G + (size_t)b * SS * 3 * QQ;
  const __half* wp2 = w16 + (size_t)(q_sub * 23) * HH + (wid << 5) + (hq << 3);

  double lp_acc = 0.0, ent_acc = 0.0;
  int first_idx = 0;

  for (int t = 0; t < SS; ++t) {
    // ---- G prefetch issue (next-step q12) ----
    const int p0 = hist[1], p1 = hist[2];
    uint2 g0raw = make_uint2(0, 0), g1raw = make_uint2(0, 0);
    const bool pf = (tid < 90);
    if (pf) {
      if (p0 >= 0) g0raw = *(const uint2*)(Gb + ((size_t)p0 * 3 + 0) * QQ + 4 * tid);
      if (p1 >= 0) g1raw = *(const uint2*)(Gb + ((size_t)p1 * 3 + 1) * QQ + 4 * tid);
    }

    // ---- hoisted P4 prologue: gumbel + mask (depends only on t / prev step) ----
    float gum, maskv;
    {
      TF2 o = threefry(c_keys.sk[t][0], c_keys.sk[t][1], 0u, (uint32_t)(b * SS + s4));
      float fb = __uint_as_float((o.b >> 9) | 0x3f800000u) - 1.0f;
      fb = fmaxf(fb, 1.0e-12f);
      gum = -__logf(-__logf(fb));
      maskv = mask_s[s4];
    }

    // ---- P2: eq over own 32-h slice; lane covers 8 h, 23 q (dwordx4 loads) ----
    {
      float a[8];
#pragma unroll
      for (int j = 0; j < 8; ++j) a[j] = 0.f;
      const float* qsp = q_s + q_sub * 23;
#pragma unroll
      for (int i = 0; i < 23; ++i) {
        uint4 raw = *(const uint4*)(wp2 + (size_t)i * HH);
        float qv = qsp[i];
        float2 f01 = __half22float2(*(const __half2*)&raw.x);
        float2 f23 = __half22float2(*(const __half2*)&raw.y);
        float2 f45 = __half22float2(*(const __half2*)&raw.z);
        float2 f67 = __half22float2(*(const __half2*)&raw.w);
        a[0] = fmaf(qv, f01.x, a[0]); a[1] = fmaf(qv, f01.y, a[1]);
        a[2] = fmaf(qv, f23.x, a[2]); a[3] = fmaf(qv, f23.y, a[3]);
        a[4] = fmaf(qv, f45.x, a[4]); a[5] = fmaf(qv, f45.y, a[5]);
        a[6] = fmaf(qv, f67.x, a[6]); a[7] = fmaf(qv, f67.y, a[7]);
      }
#pragma unroll
      for (int off = 4; off <= 32; off <<= 1)
#pragma unroll
        for (int j = 0; j < 8; ++j) a[j] += __shfl_xor(a[j], off);
      if (lane < 4) {        // q_sub==0, hq==lane
        int h0 = (wid << 5) + (lane << 3);
#pragma unroll
        for (int j = 0; j < 8; ++j) evq[h0 + j].x = EXP2F(CC * a[j]);
      }
      // no barrier: each wave reads only its own evq slice (in-wave ordering)
    }

    // ---- P3: scores from register-resident bf16 E ----
    {
      float acc[8];
#pragma unroll
      for (int j = 0; j < 8; ++j) acc[j] = 0.f;
#pragma unroll
      for (int i = 0; i < 16; ++i) {
        float2 ev = evq[(wid << 5) + 2 * i + hl];
        const float F = ev.x, mv = ev.y;
#pragma unroll
        for (int pr = 0; pr < 4; ++pr) {
          uint32_t pk = E_r[i * 4 + pr];
          float E0 = __uint_as_float(pk << 16);
          float E1 = __uint_as_float(pk & 0xFFFF0000u);
          float d0 = fmaf(E0, F, 1.0f);
          float d1 = fmaf(E1, F, 1.0f);
          acc[pr * 2 + 0] = fmaf(mv, frcp(d0), acc[pr * 2 + 0]);
          acc[pr * 2 + 1] = fmaf(mv, frcp(d1), acc[pr * 2 + 1]);
        }
      }
#pragma unroll
      for (int j = 0; j < 8; ++j) acc[j] += __shfl_xor(acc[j], 32);
      if (hl == 0) {
        *(float4*)&part[wid][sbase]     = make_float4(acc[0], acc[1], acc[2], acc[3]);
        *(float4*)&part[wid][sbase + 4] = make_float4(acc[4], acc[5], acc[6], acc[7]);
      }
    }

    // ---- consume q12 prefetch ----
    if (pf) {
      float2 f0a = __half22float2(*(const __half2*)&g0raw.x);
      float2 f0b = __half22float2(*(const __half2*)&g0raw.y);
      float2 f1a = __half22float2(*(const __half2*)&g1raw.x);
      float2 f1b = __half22float2(*(const __half2*)&g1raw.y);
      float4 qv;
      qv.x = f0a.x + f1a.x; qv.y = f0a.y + f1a.y;
      qv.z = f0b.x + f1b.x; qv.w = f0b.y + f1b.y;
      *(float4*)&q12_s[4 * tid] = qv;
    }
    __syncthreads();   // b1: part, q12 ready

    // ================== P4: all 16 waves, 4 threads per s ==================
    {
      float a = part[rq * 4 + 0][s4];
      a += part[rq * 4 + 1][s4];
      a += part[rq * 4 + 2][s4];
      a += part[rq * 4 + 3][s4];
      a += __shfl_xor(a, 1);
      a += __shfl_xor(a, 2);          // all 4 rq lanes: full 16-row sum
      float sc = Vtot + a;
      float logit = 10.0f * fast_tanh(sc);
      float m = (maskv != 0.f) ? -1.0e8f : logit;
      if (rq == 0) m_s[s4] = m;
      float z = m + gum;
      float e = __expf(m);            // masked -> exactly 0
      float em = e * m;
      int si = s4;
#pragma unroll
      for (int off = 4; off <= 32; off <<= 1) {
        float zo = __shfl_xor(z, off);
        int io = __shfl_xor(si, off);
        if (zo > z || (zo == z && io < si)) { z = zo; si = io; }
        e += __shfl_xor(e, off);
        em += __shfl_xor(em, off);
      }
      if (lane == 0) wred[wid] = make_float4(z, __int_as_float(si), e, em);
    }
    __syncthreads();   // b2: wred, m_s ready

    // ================== finalize (all threads) + next-q build ==================
    {
      float4 r0 = wred[0];
      float z = r0.x; int si = __float_as_int(r0.y);
      float se = r0.z, sem = r0.w;
#pragma unroll
      for (int r = 1; r < 16; ++r) {
        float4 rv = wred[r];
        int io = __float_as_int(rv.y);
        if (rv.x > z || (rv.x == z && io < si)) { z = rv.x; si = io; }
        se += rv.z; sem += rv.w;
      }
      const int idx = si;
      if (pf) {   // tid < 90: q_s = relu(q12 + G2[idx])
        uint2 g2 = *(const uint2*)(Gb + ((size_t)idx * 3 + 2) * QQ + 4 * tid);
        float2 f2a = __half22float2(*(const __half2*)&g2.x);
        float2 f2b = __half22float2(*(const __half2*)&g2.y);
        float4 q12v = *(const float4*)&q12_s[4 * tid];
        float4 qn;
        qn.x = fmaxf(q12v.x + f2a.x, 0.f);
        qn.y = fmaxf(q12v.y + f2a.y, 0.f);
        qn.z = fmaxf(q12v.z + f2b.x, 0.f);
        qn.w = fmaxf(q12v.w + f2b.y, 0.f);
        *(float4*)&q_s[4 * tid] = qn;
      }
      if (tid == 0) {
        float lse = __logf(se);
        float mi = m_s[idx];
        lp_acc += (double)(mi - lse);
        ent_acc += (double)(lse - sem / se);
        out[b * 257 + t] = (float)idx;
        mask_s[idx] = 1.0f;
        hist[0] = hist[1]; hist[1] = hist[2]; hist[2] = idx;
        if (t == 0) first_idx = idx;
      }
    }
    __syncthreads();   // b3: q_s, hist, mask updated
  }

  if (tid == 0) {
    out[b * 257 + 256] = (float)first_idx;
    lpb[b] = lp_acc;
    entb[b] = ent_acc;
  }
}

// ---------------- Final deterministic reduction ----------------
__global__ void k_final(const double* __restrict__ lpb,
                        const double* __restrict__ entb, float* __restrict__ out) {
  if (threadIdx.x == 0) {
    double a = 0.0, c = 0.0;
    for (int i = 0; i < BB; ++i) { a += lpb[i]; c += entb[i]; }
    out[BB * 257 + 0] = (float)a;
    out[BB * 257 + 1] = (float)c;
  }
}

extern "C" void kernel_launch(void* const* d_in, const int* in_sizes, int n_in,
                              void* d_out, int out_size, void* d_ws, size_t ws_size,
                              hipStream_t stream) {
  const float* inputs = (const float*)d_in[0];
  const float* Wc  = (const float*)d_in[1];
  const float* bc  = (const float*)d_in[2];
  const float* Wq  = (const float*)d_in[3];
  const float* w_q = (const float*)d_in[4];
  const float* v   = (const float*)d_in[5];
  float* out = (float*)d_out;

  char* ws = (char*)d_ws;
  const size_t encBytes = (size_t)BB * HH * SS;            // 16.8 MB int8
  const size_t gBytes   = (size_t)3 * BB * SS * QQ * 2;    // 70.8 MB fp16
  const size_t wqBytes  = (size_t)QP * HH * 2;             // 377 KB fp16 (padded)
  int8_t* enc8 = (int8_t*)ws;
  __half* G   = (__half*)(ws + encBytes);
  __half* w16 = (__half*)(ws + encBytes + gBytes);
  size_t goff = (encBytes + gBytes + wqBytes + 1023) & ~(size_t)1023;
  double* lpb = (double*)(ws + goff);
  double* entb = lpb + BB;

  dim3 gA1(8, BB);
  k_enc<<<gA1, 256, 0, stream>>>(inputs, Wc, bc, enc8);
  dim3 gA2(6, BB, 3);
  k_G<<<gA2, 256, 0, stream>>>(inputs, Wq, G);
  k_wq16<<<(QP * HH + 1023) / 1024, 1024, 0, stream>>>(w_q, w16);
  k_scan<<<BB, 1024, 0, stream>>>(w16, v, enc8, G, out, lpb, entb);
  k_final<<<1, 64, 0, stream>>>(lpb, entb, out);
}

// Round 6
// 8673.861 us; speedup vs baseline: 1.9704x; 1.9704x over previous
//
#include <hip/hip_runtime.h>
#include <hip/hip_fp16.h>
#include <stdint.h>

#define BB 128
#define SS 256
#define HH 512
#define QQ 360
#define QP 368    // padded q (8 subsets * 46), pad zeroed
#define QP2 184   // q-pairs

// ---------------- Threefry-2x32 (JAX semantics) ----------------
struct TF2 { uint32_t a, b; };

__host__ __device__ constexpr uint32_t rotl32(uint32_t x, int d) {
  return (x << d) | (x >> (32 - d));
}

__host__ __device__ constexpr TF2 threefry(uint32_t k0, uint32_t k1,
                                           uint32_t x0, uint32_t x1) {
  uint32_t ks[3] = {k0, k1, k0 ^ k1 ^ 0x1BD11BDAu};
  x0 += ks[0]; x1 += ks[1];
  const int R0[4] = {13, 15, 26, 6};
  const int R1[4] = {17, 29, 16, 24};
  for (int g = 0; g < 5; ++g) {
    const int* r = (g & 1) ? R1 : R0;
    for (int i = 0; i < 4; ++i) { x0 += x1; x1 = rotl32(x1, r[i]); x1 ^= x0; }
    x0 += ks[(g + 1) % 3];
    x1 += ks[(g + 2) % 3] + (uint32_t)(g + 1);
  }
  return TF2{x0, x1};
}

struct KeyTab { uint32_t sk[256][2]; };
constexpr KeyTab make_keys() {
  KeyTab K{};
  uint32_t k0 = 0u, k1 = 1u;
  for (int t = 0; t < 256; ++t) {
    TF2 nk = threefry(k0, k1, 0u, 0u);
    TF2 sk = threefry(k0, k1, 0u, 1u);
    K.sk[t][0] = sk.a; K.sk[t][1] = sk.b;
    k0 = nk.a; k1 = nk.b;
  }
  return K;
}
__constant__ KeyTab c_keys = make_keys();

// ---------------- fast math helpers ----------------
__device__ __forceinline__ float frcp(float x) {
#if __has_builtin(__builtin_amdgcn_rcpf)
  return __builtin_amdgcn_rcpf(x);
#else
  return 1.0f / x;
#endif
}

#if __has_builtin(__builtin_amdgcn_exp2f)
  #define EXP2F(x) __builtin_amdgcn_exp2f(x)
  #define CC 2.8853900817779268f
#else
  #define EXP2F(x) __expf(x)
  #define CC 2.0f
#endif

#define ENC_SCALE 21.0f
#define ENC_INV (CC / ENC_SCALE)

__device__ __forceinline__ float fast_tanh(float x) {
  float e = __expf(2.0f * x);
  return 1.0f - 2.0f * frcp(e + 1.0f);
}

typedef _Float16 f16x2 __attribute__((ext_vector_type(2)));

// ---------------- Phase A1: enc8[b][h][s] = int8( 21 * (inputs @ Wc + bc)^T ) ----------------
__global__ __launch_bounds__(256) void k_enc(const float* __restrict__ inputs,
                                             const float* __restrict__ Wc,
                                             const float* __restrict__ bc,
                                             int8_t* __restrict__ enc8) {
  const int ht = blockIdx.x;
  const int b  = blockIdx.y;
  const int tid = threadIdx.x;
  const int ts = tid & 63, th = tid >> 6;
  __shared__ float Xs[32 * 260];
  __shared__ float Ws[32 * 64];
  float acc[16][4];
#pragma unroll
  for (int i = 0; i < 16; ++i)
#pragma unroll
    for (int j = 0; j < 4; ++j) acc[i][j] = 0.f;

  const float* Arow = inputs + ((size_t)b * SS + tid) * HH;
  for (int kk = 0; kk < HH; kk += 32) {
    const float4* ip = (const float4*)(Arow + kk);
#pragma unroll
    for (int e = 0; e < 8; ++e) {
      float4 w = ip[e];
      Xs[(e * 4 + 0) * 260 + tid] = w.x;
      Xs[(e * 4 + 1) * 260 + tid] = w.y;
      Xs[(e * 4 + 2) * 260 + tid] = w.z;
      Xs[(e * 4 + 3) * 260 + tid] = w.w;
    }
    {
      int kw = tid >> 3, hw = (tid & 7) * 8;
      const float4* wp = (const float4*)(Wc + (size_t)(kk + kw) * HH + ht * 64 + hw);
      float4 w0 = wp[0], w1 = wp[1];
      float* d = Ws + kw * 64 + hw;
      ((float4*)d)[0] = w0; ((float4*)d)[1] = w1;
    }
    __syncthreads();
#pragma unroll 8
    for (int k = 0; k < 32; ++k) {
      float xr[4];
#pragma unroll
      for (int j = 0; j < 4; ++j) xr[j] = Xs[k * 260 + ts + 64 * j];
      const float4* wr4 = (const float4*)(Ws + k * 64 + th * 16);
#pragma unroll
      for (int i4 = 0; i4 < 4; ++i4) {
        float4 w = wr4[i4];
        float wv[4] = {w.x, w.y, w.z, w.w};
#pragma unroll
        for (int c = 0; c < 4; ++c)
#pragma unroll
          for (int j = 0; j < 4; ++j) acc[i4 * 4 + c][j] += wv[c] * xr[j];
      }
    }
    __syncthreads();
  }
#pragma unroll
  for (int i = 0; i < 16; ++i) {
    int h = ht * 64 + th * 16 + i;
    float bcv = bc[h];
    int8_t* orow = enc8 + (size_t)b * (HH * SS) + (size_t)h * SS + ts;
#pragma unroll
    for (int j = 0; j < 4; ++j) {
      float q = rintf(fminf(fmaxf((acc[i][j] + bcv) * ENC_SCALE, -127.f), 127.f));
      orow[64 * j] = (int8_t)(int)q;
    }
  }
}

// ---------------- Phase A2: G[b][j][k][q] = half( inputs[b,j,:] @ Wq[k] ) ----------------
__global__ __launch_bounds__(256) void k_G(const float* __restrict__ inputs,
                                           const float* __restrict__ Wq,
                                           __half* __restrict__ G) {
  const int qt = blockIdx.x;
  const int b  = blockIdx.y;
  const int k  = blockIdx.z;
  const int tid = threadIdx.x;
  const int ql = tid & 63, tj = tid >> 6;
  __shared__ float Xs[32 * 260];
  __shared__ float Ws[32 * 64];
  float acc[64];
#pragma unroll
  for (int j = 0; j < 64; ++j) acc[j] = 0.f;
  const int q = qt * 64 + ql;
  const float* Arow = inputs + ((size_t)b * SS + tid) * HH;
  const float* Wqk = Wq + (size_t)k * HH * QQ;
  for (int kk = 0; kk < HH; kk += 32) {
    const float4* ip = (const float4*)(Arow + kk);
#pragma unroll
    for (int e = 0; e < 8; ++e) {
      float4 w = ip[e];
      Xs[(e * 4 + 0) * 260 + tid] = w.x;
      Xs[(e * 4 + 1) * 260 + tid] = w.y;
      Xs[(e * 4 + 2) * 260 + tid] = w.z;
      Xs[(e * 4 + 3) * 260 + tid] = w.w;
    }
    {
      int hh = tid >> 3, qw = (tid & 7) * 8;
      const float* src = Wqk + (size_t)(kk + hh) * QQ;
      float* d = Ws + hh * 64 + qw;
#pragma unroll
      for (int e = 0; e < 8; ++e) {
        int qg = qt * 64 + qw + e;
        d[e] = (qg < QQ) ? src[qg] : 0.f;
      }
    }
    __syncthreads();
#pragma unroll 4
    for (int k2 = 0; k2 < 32; ++k2) {
      float wr = Ws[k2 * 64 + ql];
      const float4* xp = (const float4*)(Xs + k2 * 260 + tj * 64);
#pragma unroll
      for (int j4 = 0; j4 < 16; ++j4) {
        float4 x = xp[j4];
        acc[j4 * 4 + 0] += wr * x.x;
        acc[j4 * 4 + 1] += wr * x.y;
        acc[j4 * 4 + 2] += wr * x.z;
        acc[j4 * 4 + 3] += wr * x.w;
      }
    }
    __syncthreads();
  }
  if (q < QQ) {
#pragma unroll
    for (int j = 0; j < 64; ++j) {
      size_t jg = (size_t)b * SS + (tj * 64 + j);
      G[(jg * 3 + k) * QQ + q] = __float2half(acc[j]);
    }
  }
}

// ---------------- W2 pack: W2[qp][h] = half2(w_q[2qp][h], w_q[2qp+1][h]), qp<184 ----------------
__global__ __launch_bounds__(1024) void k_w2(const float* __restrict__ w_q,
                                             __half2* __restrict__ W2) {
  int t = blockIdx.x * 1024 + threadIdx.x;
  if (t < QP2 * HH) {
    int qp = t / HH, h = t % HH;
    float a = (2 * qp < QQ) ? w_q[(size_t)(2 * qp) * HH + h] : 0.f;
    float b = (2 * qp + 1 < QQ) ? w_q[(size_t)(2 * qp + 1) * HH + h] : 0.f;
    W2[t] = __floats2half2_rn(a, b);
  }
}

// ---------------- Main scan ----------------
// Register budget: 128 unified (VGPR+AGPR) at 16 waves/CU. E_r = 64 AGPRs,
// so arch-VGPR must stay <= 64 — keep load windows small (unroll 4).
// P2 via v_dot2_f32_f16 (fp16 mul, fp32 accumulate) on q-pair-packed W2:
// 23 x (16B load + 4 fdot2) per lane instead of 45 x (8B load + 4 cvt + 8 fma).
// P4 spread over all 16 waves (4 threads/s); part padded [16][260] -> 2-way reads.
__global__ __launch_bounds__(1024, 4) void k_scan(
    const __half2* __restrict__ W2, const float* __restrict__ v,
    const int8_t* __restrict__ enc8, const __half* __restrict__ G,
    float* __restrict__ out, double* __restrict__ lpb, double* __restrict__ entb) {
  const int b = blockIdx.x;
  const int tid = (int)threadIdx.x;
  const int lane = tid & 63;
  const int wid = tid >> 6;            // 16 waves
  // P2 geometry: lane = q_sub*8 + hq; q_sub 0..7 (23 q-pairs each), hq 0..7 (4 h each)
  const int q_sub = lane >> 3;
  const int hq = lane & 7;
  // P3 geometry
  const int hl = lane >> 5;            // 0..1
  const int sl = lane & 31;
  const int sbase = sl * 8;
  // P4 geometry: 4 threads per s
  const int s4 = tid >> 2;             // 0..255
  const int rq = tid & 3;              // 0..3

  __shared__ float2 evq[HH];           // .x = exp2(CC*eq[h]) (per step), .y = -2*v[h]
  __shared__ __half2 q2_s[QP2];        // current query as q-pairs (relu'd), pad zeroed
  __shared__ float q12_s[QP];          // prefetched G0+G1 for next step (float)
  __shared__ float part[16][260];      // +4 pad: P4 spread reads 2-way instead of 4-way
  __shared__ float m_s[SS];
  __shared__ float mask_s[SS];
  __shared__ float4 wred[16];
  __shared__ int hist[3];
  __shared__ float Vtot_s;

  // ---- init ----
  if (tid < HH) evq[tid] = make_float2(1.0f, -2.0f * v[tid]);  // F=exp2(0)=1
  if (tid < SS) mask_s[tid] = 0.f;
  if (tid < QP) q12_s[tid] = 0.f;
  if (tid < QP2) q2_s[tid] = __floats2half2_rn(0.f, 0.f);
  if (tid < 3) hist[tid] = -1;
  if (tid < 64) {
    float s = 0.f;
#pragma unroll
    for (int j = 0; j < 8; ++j) s += v[tid + 64 * j];
#pragma unroll
    for (int off = 32; off; off >>= 1) s += __shfl_xor(s, off);
    if (tid == 0) Vtot_s = s;
  }
  __syncthreads();
  const float Vtot = Vtot_s;

  // ---- register-resident E = exp2(ENC_INV * enc8), packed bf16 pairs (-> AGPRs) ----
  uint32_t E_r[64];
  {
    const int8_t* encW = enc8 + (size_t)b * (HH * SS) + (size_t)(wid * 32 + hl) * SS + sbase;
#pragma unroll
    for (int i = 0; i < 16; ++i) {
      uint2 w = *(const uint2*)(encW + (size_t)(2 * i) * SS);
#pragma unroll
      for (int p = 0; p < 2; ++p) {
        uint32_t wb = p ? w.y : w.x;
#pragma unroll
        for (int kp = 0; kp < 2; ++kp) {
          float f0 = (float)(int)(int8_t)(wb >> (16 * kp));
          float f1 = (float)(int)(int8_t)(wb >> (16 * kp + 8));
          float e0 = EXP2F(f0 * ENC_INV);
          float e1 = EXP2F(f1 * ENC_INV);
          uint32_t b0 = (__float_as_uint(e0) + 0x8000u) >> 16;
          uint32_t b1 = (__float_as_uint(e1) + 0x8000u) & 0xFFFF0000u;
          E_r[i * 4 + p * 2 + kp] = b0 | b1;
        }
      }
    }
  }

  const __half* Gb = G + (size_t)b * SS * 3 * QQ;
  const __half2* wp2 = W2 + (size_t)(q_sub * 23) * HH + (wid << 5) + (hq << 2);

  double lp_acc = 0.0, ent_acc = 0.0;
  int first_idx = 0;

  for (int t = 0; t < SS; ++t) {
    // ---- G prefetch issue (next-step q12) ----
    const int p0 = hist[1], p1 = hist[2];
    uint2 g0raw = make_uint2(0, 0), g1raw = make_uint2(0, 0);
    const bool pf = (tid < 90);
    if (pf) {
      if (p0 >= 0) g0raw = *(const uint2*)(Gb + ((size_t)p0 * 3 + 0) * QQ + 4 * tid);
      if (p1 >= 0) g1raw = *(const uint2*)(Gb + ((size_t)p1 * 3 + 1) * QQ + 4 * tid);
    }

    // ---- P2: eq over own 32-h slice; lane covers 4 h, 23 q-pairs (fdot2) ----
    {
      float a[4];
#pragma unroll
      for (int j = 0; j < 4; ++j) a[j] = 0.f;
      const __half2* qsp = q2_s + q_sub * 23;
#pragma unroll 4
      for (int i = 0; i < 23; ++i) {
        uint4 raw = *(const uint4*)(wp2 + (size_t)i * HH);   // 4 half2 (4 h, 1 q-pair)
        __half2 qv = qsp[i];
#if __has_builtin(__builtin_amdgcn_fdot2)
        f16x2 qf = *(f16x2*)&qv;
        a[0] = __builtin_amdgcn_fdot2(qf, *(f16x2*)&raw.x, a[0], false);
        a[1] = __builtin_amdgcn_fdot2(qf, *(f16x2*)&raw.y, a[1], false);
        a[2] = __builtin_amdgcn_fdot2(qf, *(f16x2*)&raw.z, a[2], false);
        a[3] = __builtin_amdgcn_fdot2(qf, *(f16x2*)&raw.w, a[3], false);
#else
        float2 qf = __half22float2(qv);
        float2 w0 = __half22float2(*(const __half2*)&raw.x);
        float2 w1 = __half22float2(*(const __half2*)&raw.y);
        float2 w2 = __half22float2(*(const __half2*)&raw.z);
        float2 w3 = __half22float2(*(const __half2*)&raw.w);
        a[0] = fmaf(qf.x, w0.x, fmaf(qf.y, w0.y, a[0]));
        a[1] = fmaf(qf.x, w1.x, fmaf(qf.y, w1.y, a[1]));
        a[2] = fmaf(qf.x, w2.x, fmaf(qf.y, w2.y, a[2]));
        a[3] = fmaf(qf.x, w3.x, fmaf(qf.y, w3.y, a[3]));
#endif
      }
#pragma unroll
      for (int off = 8; off <= 32; off <<= 1)
#pragma unroll
        for (int j = 0; j < 4; ++j) a[j] += __shfl_xor(a[j], off);
      if (lane < 8) {        // q_sub==0, hq==lane
        int h0 = (wid << 5) + (lane << 2);
        evq[h0 + 0].x = EXP2F(CC * a[0]);
        evq[h0 + 1].x = EXP2F(CC * a[1]);
        evq[h0 + 2].x = EXP2F(CC * a[2]);
        evq[h0 + 3].x = EXP2F(CC * a[3]);
      }
      // no barrier: each wave reads only its own evq slice (in-wave ordering)
    }

    // ---- P3: scores from register-resident bf16 E ----
    {
      float acc[8];
#pragma unroll
      for (int j = 0; j < 8; ++j) acc[j] = 0.f;
#pragma unroll
      for (int i = 0; i < 16; ++i) {
        float2 ev = evq[(wid << 5) + 2 * i + hl];
        const float F = ev.x, mv = ev.y;
#pragma unroll
        for (int pr = 0; pr < 4; ++pr) {
          uint32_t pk = E_r[i * 4 + pr];
          float E0 = __uint_as_float(pk << 16);
          float E1 = __uint_as_float(pk & 0xFFFF0000u);
          float d0 = fmaf(E0, F, 1.0f);
          float d1 = fmaf(E1, F, 1.0f);
          acc[pr * 2 + 0] = fmaf(mv, frcp(d0), acc[pr * 2 + 0]);
          acc[pr * 2 + 1] = fmaf(mv, frcp(d1), acc[pr * 2 + 1]);
        }
      }
#pragma unroll
      for (int j = 0; j < 8; ++j) acc[j] += __shfl_xor(acc[j], 32);
      if (hl == 0) {
        *(float4*)&part[wid][sbase]     = make_float4(acc[0], acc[1], acc[2], acc[3]);
        *(float4*)&part[wid][sbase + 4] = make_float4(acc[4], acc[5], acc[6], acc[7]);
      }
    }

    // ---- consume q12 prefetch ----
    if (pf) {
      float2 f0a = __half22float2(*(const __half2*)&g0raw.x);
      float2 f0b = __half22float2(*(const __half2*)&g0raw.y);
      float2 f1a = __half22float2(*(const __half2*)&g1raw.x);
      float2 f1b = __half22float2(*(const __half2*)&g1raw.y);
      float4 qv;
      qv.x = f0a.x + f1a.x; qv.y = f0a.y + f1a.y;
      qv.z = f0b.x + f1b.x; qv.w = f0b.y + f1b.y;
      *(float4*)&q12_s[4 * tid] = qv;
    }

    // ---- gumbel + mask for P4 (2 regs live across b1 only) ----
    float gum, maskv;
    {
      TF2 o = threefry(c_keys.sk[t][0], c_keys.sk[t][1], 0u, (uint32_t)(b * SS + s4));
      float fb = __uint_as_float((o.b >> 9) | 0x3f800000u) - 1.0f;
      fb = fmaxf(fb, 1.0e-12f);
      gum = -__logf(-__logf(fb));
      maskv = mask_s[s4];
    }
    __syncthreads();   // b1: part, q12 ready

    // ================== P4: all 16 waves, 4 threads per s ==================
    {
      float a = part[rq * 4 + 0][s4];
      a += part[rq * 4 + 1][s4];
      a += part[rq * 4 + 2][s4];
      a += part[rq * 4 + 3][s4];
      a += __shfl_xor(a, 1);
      a += __shfl_xor(a, 2);          // all 4 rq lanes: full 16-row sum
      float sc = Vtot + a;
      float logit = 10.0f * fast_tanh(sc);
      float m = (maskv != 0.f) ? -1.0e8f : logit;
      if (rq == 0) m_s[s4] = m;
      float z = m + gum;
      float e = __expf(m);            // masked -> exactly 0
      float em = e * m;
      int si = s4;
#pragma unroll
      for (int off = 4; off <= 32; off <<= 1) {
        float zo = __shfl_xor(z, off);
        int io = __shfl_xor(si, off);
        if (zo > z || (zo == z && io < si)) { z = zo; si = io; }
        e += __shfl_xor(e, off);
        em += __shfl_xor(em, off);
      }
      if (lane == 0) wred[wid] = make_float4(z, __int_as_float(si), e, em);
    }
    __syncthreads();   // b2: wred, m_s ready

    // ================== finalize (all threads) + next-q build ==================
    {
      float4 r0 = wred[0];
      float z = r0.x; int si = __float_as_int(r0.y);
      float se = r0.z, sem = r0.w;
#pragma unroll
      for (int r = 1; r < 16; ++r) {
        float4 rv = wred[r];
        int io = __float_as_int(rv.y);
        if (rv.x > z || (rv.x == z && io < si)) { z = rv.x; si = io; }
        se += rv.z; sem += rv.w;
      }
      const int idx = si;
      if (pf) {   // tid < 90: q = relu(q12 + G2[idx]) -> q2_s half2 pairs
        uint2 g2 = *(const uint2*)(Gb + ((size_t)idx * 3 + 2) * QQ + 4 * tid);
        float2 f2a = __half22float2(*(const __half2*)&g2.x);
        float2 f2b = __half22float2(*(const __half2*)&g2.y);
        float4 q12v = *(const float4*)&q12_s[4 * tid];
        float4 qn;
        qn.x = fmaxf(q12v.x + f2a.x, 0.f);
        qn.y = fmaxf(q12v.y + f2a.y, 0.f);
        qn.z = fmaxf(q12v.z + f2b.x, 0.f);
        qn.w = fmaxf(q12v.w + f2b.y, 0.f);
        q2_s[2 * tid]     = __floats2half2_rn(qn.x, qn.y);
        q2_s[2 * tid + 1] = __floats2half2_rn(qn.z, qn.w);
      }
      if (tid == 0) {
        float lse = __logf(se);
        float mi = m_s[idx];
        lp_acc += (double)(mi - lse);
        ent_acc += (double)(lse - sem / se);
        out[b * 257 + t] = (float)idx;
        mask_s[idx] = 1.0f;
        hist[0] = hist[1]; hist[1] = hist[2]; hist[2] = idx;
        if (t == 0) first_idx = idx;
      }
    }
    __syncthreads();   // b3: q2_s, hist, mask updated
  }

  if (tid == 0) {
    out[b * 257 + 256] = (float)first_idx;
    lpb[b] = lp_acc;
    entb[b] = ent_acc;
  }
}

// ---------------- Final deterministic reduction ----------------
__global__ void k_final(const double* __restrict__ lpb,
                        const double* __restrict__ entb, float* __restrict__ out) {
  if (threadIdx.x == 0) {
    double a = 0.0, c = 0.0;
    for (int i = 0; i < BB; ++i) { a += lpb[i]; c += entb[i]; }
    out[BB * 257 + 0] = (float)a;
    out[BB * 257 + 1] = (float)c;
  }
}

extern "C" void kernel_launch(void* const* d_in, const int* in_sizes, int n_in,
                              void* d_out, int out_size, void* d_ws, size_t ws_size,
                              hipStream_t stream) {
  const float* inputs = (const float*)d_in[0];
  const float* Wc  = (const float*)d_in[1];
  const float* bc  = (const float*)d_in[2];
  const float* Wq  = (const float*)d_in[3];
  const float* w_q = (const float*)d_in[4];
  const float* v   = (const float*)d_in[5];
  float* out = (float*)d_out;

  char* ws = (char*)d_ws;
  const size_t encBytes = (size_t)BB * HH * SS;            // 16.8 MB int8
  const size_t gBytes   = (size_t)3 * BB * SS * QQ * 2;    // 70.8 MB fp16
  const size_t w2Bytes  = (size_t)QP2 * HH * 4;            // 377 KB half2 (q-pair packed)
  int8_t* enc8 = (int8_t*)ws;
  __half* G   = (__half*)(ws + encBytes);
  __half2* W2 = (__half2*)(ws + encBytes + gBytes);
  size_t goff = (encBytes + gBytes + w2Bytes + 1023) & ~(size_t)1023;
  double* lpb = (double*)(ws + goff);
  double* entb = lpb + BB;

  dim3 gA1(8, BB);
  k_enc<<<gA1, 256, 0, stream>>>(inputs, Wc, bc, enc8);
  dim3 gA2(6, BB, 3);
  k_G<<<gA2, 256, 0, stream>>>(inputs, Wq, G);
  k_w2<<<(QP2 * HH + 1023) / 1024, 1024, 0, stream>>>(w_q, W2);
  k_scan<<<BB, 1024, 0, stream>>>(W2, v, enc8, G, out, lpb, entb);
  k_final<<<1, 64, 0, stream>>>(lpb, entb, out);
}

// Round 8
// 8058.633 us; speedup vs baseline: 2.1208x; 1.0763x over previous
//
#include <hip/hip_runtime.h>
#include <hip/hip_fp16.h>
#include <stdint.h>

#define BB 128
#define SS 256
#define HH 512
#define QQ 360
#define QP 368    // padded q, pad zeroed
#define QP2 184   // q-pairs

// ---------------- Threefry-2x32 (JAX semantics) ----------------
struct TF2 { uint32_t a, b; };

__host__ __device__ constexpr uint32_t rotl32(uint32_t x, int d) {
  return (x << d) | (x >> (32 - d));
}

__host__ __device__ constexpr TF2 threefry(uint32_t k0, uint32_t k1,
                                           uint32_t x0, uint32_t x1) {
  uint32_t ks[3] = {k0, k1, k0 ^ k1 ^ 0x1BD11BDAu};
  x0 += ks[0]; x1 += ks[1];
  const int R0[4] = {13, 15, 26, 6};
  const int R1[4] = {17, 29, 16, 24};
  for (int g = 0; g < 5; ++g) {
    const int* r = (g & 1) ? R1 : R0;
    for (int i = 0; i < 4; ++i) { x0 += x1; x1 = rotl32(x1, r[i]); x1 ^= x0; }
    x0 += ks[(g + 1) % 3];
    x1 += ks[(g + 2) % 3] + (uint32_t)(g + 1);
  }
  return TF2{x0, x1};
}

struct KeyTab { uint32_t sk[256][2]; };
constexpr KeyTab make_keys() {
  KeyTab K{};
  uint32_t k0 = 0u, k1 = 1u;
  for (int t = 0; t < 256; ++t) {
    TF2 nk = threefry(k0, k1, 0u, 0u);
    TF2 sk = threefry(k0, k1, 0u, 1u);
    K.sk[t][0] = sk.a; K.sk[t][1] = sk.b;
    k0 = nk.a; k1 = nk.b;
  }
  return K;
}
__constant__ KeyTab c_keys = make_keys();

// ---------------- fast math helpers ----------------
__device__ __forceinline__ float frcp(float x) {
#if __has_builtin(__builtin_amdgcn_rcpf)
  return __builtin_amdgcn_rcpf(x);
#else
  return 1.0f / x;
#endif
}

#if __has_builtin(__builtin_amdgcn_exp2f)
  #define EXP2F(x) __builtin_amdgcn_exp2f(x)
  #define CC 2.8853900817779268f
#else
  #define EXP2F(x) __expf(x)
  #define CC 2.0f
#endif

#define ENC_SCALE 21.0f
#define ENC_INV (CC / ENC_SCALE)

__device__ __forceinline__ float fast_tanh(float x) {
  float e = __expf(2.0f * x);
  return 1.0f - 2.0f * frcp(e + 1.0f);
}

typedef _Float16 f16x2 __attribute__((ext_vector_type(2)));

// ---------------- Phase A1: enc8[b][h][s] = int8( 21 * (inputs @ Wc + bc)^T ) ----------------
__global__ __launch_bounds__(256) void k_enc(const float* __restrict__ inputs,
                                             const float* __restrict__ Wc,
                                             const float* __restrict__ bc,
                                             int8_t* __restrict__ enc8) {
  const int ht = blockIdx.x;
  const int b  = blockIdx.y;
  const int tid = threadIdx.x;
  const int ts = tid & 63, th = tid >> 6;
  __shared__ float Xs[32 * 260];
  __shared__ float Ws[32 * 64];
  float acc[16][4];
#pragma unroll
  for (int i = 0; i < 16; ++i)
#pragma unroll
    for (int j = 0; j < 4; ++j) acc[i][j] = 0.f;

  const float* Arow = inputs + ((size_t)b * SS + tid) * HH;
  for (int kk = 0; kk < HH; kk += 32) {
    const float4* ip = (const float4*)(Arow + kk);
#pragma unroll
    for (int e = 0; e < 8; ++e) {
      float4 w = ip[e];
      Xs[(e * 4 + 0) * 260 + tid] = w.x;
      Xs[(e * 4 + 1) * 260 + tid] = w.y;
      Xs[(e * 4 + 2) * 260 + tid] = w.z;
      Xs[(e * 4 + 3) * 260 + tid] = w.w;
    }
    {
      int kw = tid >> 3, hw = (tid & 7) * 8;
      const float4* wp = (const float4*)(Wc + (size_t)(kk + kw) * HH + ht * 64 + hw);
      float4 w0 = wp[0], w1 = wp[1];
      float* d = Ws + kw * 64 + hw;
      ((float4*)d)[0] = w0; ((float4*)d)[1] = w1;
    }
    __syncthreads();
#pragma unroll 8
    for (int k = 0; k < 32; ++k) {
      float xr[4];
#pragma unroll
      for (int j = 0; j < 4; ++j) xr[j] = Xs[k * 260 + ts + 64 * j];
      const float4* wr4 = (const float4*)(Ws + k * 64 + th * 16);
#pragma unroll
      for (int i4 = 0; i4 < 4; ++i4) {
        float4 w = wr4[i4];
        float wv[4] = {w.x, w.y, w.z, w.w};
#pragma unroll
        for (int c = 0; c < 4; ++c)
#pragma unroll
          for (int j = 0; j < 4; ++j) acc[i4 * 4 + c][j] += wv[c] * xr[j];
      }
    }
    __syncthreads();
  }
#pragma unroll
  for (int i = 0; i < 16; ++i) {
    int h = ht * 64 + th * 16 + i;
    float bcv = bc[h];
    int8_t* orow = enc8 + (size_t)b * (HH * SS) + (size_t)h * SS + ts;
#pragma unroll
    for (int j = 0; j < 4; ++j) {
      float q = rintf(fminf(fmaxf((acc[i][j] + bcv) * ENC_SCALE, -127.f), 127.f));
      orow[64 * j] = (int8_t)(int)q;
    }
  }
}

// ---------------- Phase A2: G[b][j][k][q] = half( inputs[b,j,:] @ Wq[k] ) ----------------
__global__ __launch_bounds__(256) void k_G(const float* __restrict__ inputs,
                                           const float* __restrict__ Wq,
                                           __half* __restrict__ G) {
  const int qt = blockIdx.x;
  const int b  = blockIdx.y;
  const int k  = blockIdx.z;
  const int tid = threadIdx.x;
  const int ql = tid & 63, tj = tid >> 6;
  __shared__ float Xs[32 * 260];
  __shared__ float Ws[32 * 64];
  float acc[64];
#pragma unroll
  for (int j = 0; j < 64; ++j) acc[j] = 0.f;
  const int q = qt * 64 + ql;
  const float* Arow = inputs + ((size_t)b * SS + tid) * HH;
  const float* Wqk = Wq + (size_t)k * HH * QQ;
  for (int kk = 0; kk < HH; kk += 32) {
    const float4* ip = (const float4*)(Arow + kk);
#pragma unroll
    for (int e = 0; e < 8; ++e) {
      float4 w = ip[e];
      Xs[(e * 4 + 0) * 260 + tid] = w.x;
      Xs[(e * 4 + 1) * 260 + tid] = w.y;
      Xs[(e * 4 + 2) * 260 + tid] = w.z;
      Xs[(e * 4 + 3) * 260 + tid] = w.w;
    }
    {
      int hh = tid >> 3, qw = (tid & 7) * 8;
      const float* src = Wqk + (size_t)(kk + hh) * QQ;
      float* d = Ws + hh * 64 + qw;
#pragma unroll
      for (int e = 0; e < 8; ++e) {
        int qg = qt * 64 + qw + e;
        d[e] = (qg < QQ) ? src[qg] : 0.f;
      }
    }
    __syncthreads();
#pragma unroll 4
    for (int k2 = 0; k2 < 32; ++k2) {
      float wr = Ws[k2 * 64 + ql];
      const float4* xp = (const float4*)(Xs + k2 * 260 + tj * 64);
#pragma unroll
      for (int j4 = 0; j4 < 16; ++j4) {
        float4 x = xp[j4];
        acc[j4 * 4 + 0] += wr * x.x;
        acc[j4 * 4 + 1] += wr * x.y;
        acc[j4 * 4 + 2] += wr * x.z;
        acc[j4 * 4 + 3] += wr * x.w;
      }
    }
    __syncthreads();
  }
  if (q < QQ) {
#pragma unroll
    for (int j = 0; j < 64; ++j) {
      size_t jg = (size_t)b * SS + (tj * 64 + j);
      G[(jg * 3 + k) * QQ + q] = __float2half(acc[j]);
    }
  }
}

// ---------------- W2 pack: W2[qp][h] = half2(w_q[2qp][h], w_q[2qp+1][h]), qp<184 ----------------
__global__ __launch_bounds__(1024) void k_w2(const float* __restrict__ w_q,
                                             __half2* __restrict__ W2) {
  int t = blockIdx.x * 1024 + threadIdx.x;
  if (t < QP2 * HH) {
    int qp = t / HH, h = t % HH;
    float a = (2 * qp < QQ) ? w_q[(size_t)(2 * qp) * HH + h] : 0.f;
    float b = (2 * qp + 1 < QQ) ? w_q[(size_t)(2 * qp + 1) * HH + h] : 0.f;
    W2[t] = __floats2half2_rn(a, b);
  }
}

// ---------------- Main scan ----------------
// Register discipline (lesson of rounds 4-6): NO 64-reg arrays. enc_r int8
// (uint2[16] = 32 VGPRs) is the only large resident state — proven to stay
// in registers at VGPR=64 (rounds 0-2). P3 pays 2 trans/element (exp2+rcp);
// measured cost of that vs 1 trans was only ~2% (round 2->3).
// Structural levers kept from round 6:
//  - P2 via v_dot2_f32_f16 on q-pair-packed W2 (23 x 16B loads, unroll 4).
//  - threefry/Gumbel + mask hoisted before b1 (2 regs across one barrier).
//  - P4 spread over all 16 waves (4 threads/s), part padded [16][260].
__global__ __launch_bounds__(1024, 4) void k_scan(
    const __half2* __restrict__ W2, const float* __restrict__ v,
    const int8_t* __restrict__ enc8, const __half* __restrict__ G,
    float* __restrict__ out, double* __restrict__ lpb, double* __restrict__ entb) {
  const int b = blockIdx.x;
  const int tid = (int)threadIdx.x;
  const int lane = tid & 63;
  const int wid = tid >> 6;            // 16 waves
  // P2 geometry: lane = q_sub*8 + hq; q_sub 0..7 (23 q-pairs each), hq 0..7 (4 h each)
  const int q_sub = lane >> 3;
  const int hq = lane & 7;
  // P3 geometry
  const int hl = lane >> 5;            // 0..1
  const int sl = lane & 31;
  const int sbase = sl * 8;
  // P4 geometry: 4 threads per s
  const int s4 = tid >> 2;             // 0..255
  const int rq = tid & 3;              // 0..3

  __shared__ float2 evq[HH];           // .x = CC*eq[h] (per step), .y = -2*v[h]
  __shared__ __half2 q2_s[QP2];        // current query as q-pairs (relu'd), pad zeroed
  __shared__ float q12_s[QP];          // prefetched G0+G1 for next step (float)
  __shared__ float part[16][260];      // +4 pad: P4 spread reads near-conflict-free
  __shared__ float m_s[SS];
  __shared__ float mask_s[SS];
  __shared__ float4 wred[16];
  __shared__ int hist[3];
  __shared__ float Vtot_s;

  // ---- init ----
  if (tid < HH) evq[tid] = make_float2(0.f, -2.0f * v[tid]);
  if (tid < SS) mask_s[tid] = 0.f;
  if (tid < QP) q12_s[tid] = 0.f;
  if (tid < QP2) q2_s[tid] = __floats2half2_rn(0.f, 0.f);
  if (tid < 3) hist[tid] = -1;
  if (tid < 64) {
    float s = 0.f;
#pragma unroll
    for (int j = 0; j < 8; ++j) s += v[tid + 64 * j];
#pragma unroll
    for (int off = 32; off; off >>= 1) s += __shfl_xor(s, off);
    if (tid == 0) Vtot_s = s;
  }
  __syncthreads();
  const float Vtot = Vtot_s;

  // ---- register-resident int8 enc slice (32 VGPRs, proven resident) ----
  uint2 enc_r[16];
  {
    const int8_t* encW = enc8 + (size_t)b * (HH * SS) + (size_t)(wid * 32 + hl) * SS + sbase;
#pragma unroll
    for (int i = 0; i < 16; ++i)
      enc_r[i] = *(const uint2*)(encW + (size_t)(2 * i) * SS);
  }

  const __half* Gb = G + (size_t)b * SS * 3 * QQ;
  const __half2* wp2 = W2 + (size_t)(q_sub * 23) * HH + (wid << 5) + (hq << 2);

  double lp_acc = 0.0, ent_acc = 0.0;
  int first_idx = 0;

  for (int t = 0; t < SS; ++t) {
    // ---- G prefetch issue (next-step q12) ----
    const int p0 = hist[1], p1 = hist[2];
    uint2 g0raw = make_uint2(0, 0), g1raw = make_uint2(0, 0);
    const bool pf = (tid < 90);
    if (pf) {
      if (p0 >= 0) g0raw = *(const uint2*)(Gb + ((size_t)p0 * 3 + 0) * QQ + 4 * tid);
      if (p1 >= 0) g1raw = *(const uint2*)(Gb + ((size_t)p1 * 3 + 1) * QQ + 4 * tid);
    }

    // ---- P2: eq over own 32-h slice; lane covers 4 h, 23 q-pairs (fdot2) ----
    {
      float a[4];
#pragma unroll
      for (int j = 0; j < 4; ++j) a[j] = 0.f;
      const __half2* qsp = q2_s + q_sub * 23;
#pragma unroll 4
      for (int i = 0; i < 23; ++i) {
        uint4 raw = *(const uint4*)(wp2 + (size_t)i * HH);   // 4 half2 (4 h, 1 q-pair)
        __half2 qv = qsp[i];
#if __has_builtin(__builtin_amdgcn_fdot2)
        f16x2 qf = *(f16x2*)&qv;
        a[0] = __builtin_amdgcn_fdot2(qf, *(f16x2*)&raw.x, a[0], false);
        a[1] = __builtin_amdgcn_fdot2(qf, *(f16x2*)&raw.y, a[1], false);
        a[2] = __builtin_amdgcn_fdot2(qf, *(f16x2*)&raw.z, a[2], false);
        a[3] = __builtin_amdgcn_fdot2(qf, *(f16x2*)&raw.w, a[3], false);
#else
        float2 qf = __half22float2(qv);
        float2 w0 = __half22float2(*(const __half2*)&raw.x);
        float2 w1 = __half22float2(*(const __half2*)&raw.y);
        float2 w2 = __half22float2(*(const __half2*)&raw.z);
        float2 w3 = __half22float2(*(const __half2*)&raw.w);
        a[0] = fmaf(qf.x, w0.x, fmaf(qf.y, w0.y, a[0]));
        a[1] = fmaf(qf.x, w1.x, fmaf(qf.y, w1.y, a[1]));
        a[2] = fmaf(qf.x, w2.x, fmaf(qf.y, w2.y, a[2]));
        a[3] = fmaf(qf.x, w3.x, fmaf(qf.y, w3.y, a[3]));
#endif
      }
#pragma unroll
      for (int off = 8; off <= 32; off <<= 1)
#pragma unroll
        for (int j = 0; j < 4; ++j) a[j] += __shfl_xor(a[j], off);
      if (lane < 8) {        // q_sub==0, hq==lane
        int h0 = (wid << 5) + (lane << 2);
        evq[h0 + 0].x = CC * a[0];
        evq[h0 + 1].x = CC * a[1];
        evq[h0 + 2].x = CC * a[2];
        evq[h0 + 3].x = CC * a[3];
      }
      // no barrier: each wave reads only its own evq slice (in-wave ordering)
    }

    // ---- P3: scores from register-resident int8 enc ----
    {
      float acc[8];
#pragma unroll
      for (int j = 0; j < 8; ++j) acc[j] = 0.f;
#pragma unroll
      for (int i = 0; i < 16; ++i) {
        float2 ev = evq[(wid << 5) + 2 * i + hl];
        const float eqC = ev.x, mv = ev.y;
        const uint32_t w0 = enc_r[i].x, w1 = enc_r[i].y;
#pragma unroll
        for (int k = 0; k < 4; ++k) {
          {
            float f = (float)(int)(int8_t)(w0 >> (8 * k));
            float e = EXP2F(fmaf(f, ENC_INV, eqC));
            acc[k] = fmaf(mv, frcp(e + 1.0f), acc[k]);
          }
          {
            float f = (float)(int)(int8_t)(w1 >> (8 * k));
            float e = EXP2F(fmaf(f, ENC_INV, eqC));
            acc[4 + k] = fmaf(mv, frcp(e + 1.0f), acc[4 + k]);
          }
        }
      }
#pragma unroll
      for (int j = 0; j < 8; ++j) acc[j] += __shfl_xor(acc[j], 32);
      if (hl == 0) {
        *(float4*)&part[wid][sbase]     = make_float4(acc[0], acc[1], acc[2], acc[3]);
        *(float4*)&part[wid][sbase + 4] = make_float4(acc[4], acc[5], acc[6], acc[7]);
      }
    }

    // ---- consume q12 prefetch ----
    if (pf) {
      float2 f0a = __half22float2(*(const __half2*)&g0raw.x);
      float2 f0b = __half22float2(*(const __half2*)&g0raw.y);
      float2 f1a = __half22float2(*(const __half2*)&g1raw.x);
      float2 f1b = __half22float2(*(const __half2*)&g1raw.y);
      float4 qv;
      qv.x = f0a.x + f1a.x; qv.y = f0a.y + f1a.y;
      qv.z = f0b.x + f1b.x; qv.w = f0b.y + f1b.y;
      *(float4*)&q12_s[4 * tid] = qv;
    }

    // ---- gumbel + mask for P4 (2 regs live across b1 only) ----
    float gum, maskv;
    {
      TF2 o = threefry(c_keys.sk[t][0], c_keys.sk[t][1], 0u, (uint32_t)(b * SS + s4));
      float fb = __uint_as_float((o.b >> 9) | 0x3f800000u) - 1.0f;
      fb = fmaxf(fb, 1.0e-12f);
      gum = -__logf(-__logf(fb));
      maskv = mask_s[s4];
    }
    __syncthreads();   // b1: part, q12 ready

    // ================== P4: all 16 waves, 4 threads per s ==================
    {
      float a = part[rq * 4 + 0][s4];
      a += part[rq * 4 + 1][s4];
      a += part[rq * 4 + 2][s4];
      a += part[rq * 4 + 3][s4];
      a += __shfl_xor(a, 1);
      a += __shfl_xor(a, 2);          // all 4 rq lanes: full 16-row sum
      float sc = Vtot + a;
      float logit = 10.0f * fast_tanh(sc);
      float m = (maskv != 0.f) ? -1.0e8f : logit;
      if (rq == 0) m_s[s4] = m;
      float z = m + gum;
      float e = __expf(m);            // masked -> exactly 0
      float em = e * m;
      int si = s4;
#pragma unroll
      for (int off = 4; off <= 32; off <<= 1) {
        float zo = __shfl_xor(z, off);
        int io = __shfl_xor(si, off);
        if (zo > z || (zo == z && io < si)) { z = zo; si = io; }
        e += __shfl_xor(e, off);
        em += __shfl_xor(em, off);
      }
      if (lane == 0) wred[wid] = make_float4(z, __int_as_float(si), e, em);
    }
    __syncthreads();   // b2: wred, m_s ready

    // ================== finalize (all threads) + next-q build ==================
    {
      float4 r0 = wred[0];
      float z = r0.x; int si = __float_as_int(r0.y);
      float se = r0.z, sem = r0.w;
#pragma unroll
      for (int r = 1; r < 16; ++r) {
        float4 rv = wred[r];
        int io = __float_as_int(rv.y);
        if (rv.x > z || (rv.x == z && io < si)) { z = rv.x; si = io; }
        se += rv.z; sem += rv.w;
      }
      const int idx = si;
      if (pf) {   // tid < 90: q = relu(q12 + G2[idx]) -> q2_s half2 pairs
        uint2 g2 = *(const uint2*)(Gb + ((size_t)idx * 3 + 2) * QQ + 4 * tid);
        float2 f2a = __half22float2(*(const __half2*)&g2.x);
        float2 f2b = __half22float2(*(const __half2*)&g2.y);
        float4 q12v = *(const float4*)&q12_s[4 * tid];
        float4 qn;
        qn.x = fmaxf(q12v.x + f2a.x, 0.f);
        qn.y = fmaxf(q12v.y + f2a.y, 0.f);
        qn.z = fmaxf(q12v.z + f2b.x, 0.f);
        qn.w = fmaxf(q12v.w + f2b.y, 0.f);
        q2_s[2 * tid]     = __floats2half2_rn(qn.x, qn.y);
        q2_s[2 * tid + 1] = __floats2half2_rn(qn.z, qn.w);
      }
      if (tid == 0) {
        float lse = __logf(se);
        float mi = m_s[idx];
        lp_acc += (double)(mi - lse);
        ent_acc += (double)(lse - sem / se);
        out[b * 257 + t] = (float)idx;
        mask_s[idx] = 1.0f;
        hist[0] = hist[1]; hist[1] = hist[2]; hist[2] = idx;
        if (t == 0) first_idx = idx;
      }
    }
    __syncthreads();   // b3: q2_s, hist, mask updated
  }

  if (tid == 0) {
    out[b * 257 + 256] = (float)first_idx;
    lpb[b] = lp_acc;
    entb[b] = ent_acc;
  }
}

// ---------------- Final deterministic reduction ----------------
__global__ void k_final(const double* __restrict__ lpb,
                        const double* __restrict__ entb, float* __restrict__ out) {
  if (threadIdx.x == 0) {
    double a = 0.0, c = 0.0;
    for (int i = 0; i < BB; ++i) { a += lpb[i]; c += entb[i]; }
    out[BB * 257 + 0] = (float)a;
    out[BB * 257 + 1] = (float)c;
  }
}

extern "C" void kernel_launch(void* const* d_in, const int* in_sizes, int n_in,
                              void* d_out, int out_size, void* d_ws, size_t ws_size,
                              hipStream_t stream) {
  const float* inputs = (const float*)d_in[0];
  const float* Wc  = (const float*)d_in[1];
  const float* bc  = (const float*)d_in[2];
  const float* Wq  = (const float*)d_in[3];
  const float* w_q = (const float*)d_in[4];
  const float* v   = (const float*)d_in[5];
  float* out = (float*)d_out;

  char* ws = (char*)d_ws;
  const size_t encBytes = (size_t)BB * HH * SS;            // 16.8 MB int8
  const size_t gBytes   = (size_t)3 * BB * SS * QQ * 2;    // 70.8 MB fp16
  const size_t w2Bytes  = (size_t)QP2 * HH * 4;            // 377 KB half2 (q-pair packed)
  int8_t* enc8 = (int8_t*)ws;
  __half* G   = (__half*)(ws + encBytes);
  __half2* W2 = (__half2*)(ws + encBytes + gBytes);
  size_t goff = (encBytes + gBytes + w2Bytes + 1023) & ~(size_t)1023;
  double* lpb = (double*)(ws + goff);
  double* entb = lpb + BB;

  dim3 gA1(8, BB);
  k_enc<<<gA1, 256, 0, stream>>>(inputs, Wc, bc, enc8);
  dim3 gA2(6, BB, 3);
  k_G<<<gA2, 256, 0, stream>>>(inputs, Wq, G);
  k_w2<<<(QP2 * HH + 1023) / 1024, 1024, 0, stream>>>(w_q, W2);
  k_scan<<<BB, 1024, 0, stream>>>(W2, v, enc8, G, out, lpb, entb);
  k_final<<<1, 64, 0, stream>>>(lpb, entb, out);
}

// Round 9
// 8023.021 us; speedup vs baseline: 2.1302x; 1.0044x over previous
//
#include <hip/hip_runtime.h>
#include <hip/hip_fp16.h>
#include <stdint.h>

#define BB 128
#define SS 256
#define HH 512
#define QQ 360
#define QP 368    // padded q, pad zeroed
#define QP2 184   // q-pairs

// ---------------- Threefry-2x32 (JAX semantics) ----------------
struct TF2 { uint32_t a, b; };

__host__ __device__ constexpr uint32_t rotl32(uint32_t x, int d) {
  return (x << d) | (x >> (32 - d));
}

__host__ __device__ constexpr TF2 threefry(uint32_t k0, uint32_t k1,
                                           uint32_t x0, uint32_t x1) {
  uint32_t ks[3] = {k0, k1, k0 ^ k1 ^ 0x1BD11BDAu};
  x0 += ks[0]; x1 += ks[1];
  const int R0[4] = {13, 15, 26, 6};
  const int R1[4] = {17, 29, 16, 24};
  for (int g = 0; g < 5; ++g) {
    const int* r = (g & 1) ? R1 : R0;
    for (int i = 0; i < 4; ++i) { x0 += x1; x1 = rotl32(x1, r[i]); x1 ^= x0; }
    x0 += ks[(g + 1) % 3];
    x1 += ks[(g + 2) % 3] + (uint32_t)(g + 1);
  }
  return TF2{x0, x1};
}

struct KeyTab { uint32_t sk[256][2]; };
constexpr KeyTab make_keys() {
  KeyTab K{};
  uint32_t k0 = 0u, k1 = 1u;
  for (int t = 0; t < 256; ++t) {
    TF2 nk = threefry(k0, k1, 0u, 0u);
    TF2 sk = threefry(k0, k1, 0u, 1u);
    K.sk[t][0] = sk.a; K.sk[t][1] = sk.b;
    k0 = nk.a; k1 = nk.b;
  }
  return K;
}
__constant__ KeyTab c_keys = make_keys();

// ---------------- fast math helpers ----------------
__device__ __forceinline__ float frcp(float x) {
#if __has_builtin(__builtin_amdgcn_rcpf)
  return __builtin_amdgcn_rcpf(x);
#else
  return 1.0f / x;
#endif
}

#if __has_builtin(__builtin_amdgcn_exp2f)
  #define EXP2F(x) __builtin_amdgcn_exp2f(x)
  #define CC 2.8853900817779268f
#else
  #define EXP2F(x) __expf(x)
  #define CC 2.0f
#endif

#define ENC_SCALE 21.0f
#define ENC_INV (CC / ENC_SCALE)

__device__ __forceinline__ float fast_tanh(float x) {
  float e = __expf(2.0f * x);
  return 1.0f - 2.0f * frcp(e + 1.0f);
}

typedef _Float16 f16x2 __attribute__((ext_vector_type(2)));

// ---------------- Phase A1: enc8[b][h][s] = int8( 21 * (inputs @ Wc + bc)^T ) ----------------
__global__ __launch_bounds__(256) void k_enc(const float* __restrict__ inputs,
                                             const float* __restrict__ Wc,
                                             const float* __restrict__ bc,
                                             int8_t* __restrict__ enc8) {
  const int ht = blockIdx.x;
  const int b  = blockIdx.y;
  const int tid = threadIdx.x;
  const int ts = tid & 63, th = tid >> 6;
  __shared__ float Xs[32 * 260];
  __shared__ float Ws[32 * 64];
  float acc[16][4];
#pragma unroll
  for (int i = 0; i < 16; ++i)
#pragma unroll
    for (int j = 0; j < 4; ++j) acc[i][j] = 0.f;

  const float* Arow = inputs + ((size_t)b * SS + tid) * HH;
  for (int kk = 0; kk < HH; kk += 32) {
    const float4* ip = (const float4*)(Arow + kk);
#pragma unroll
    for (int e = 0; e < 8; ++e) {
      float4 w = ip[e];
      Xs[(e * 4 + 0) * 260 + tid] = w.x;
      Xs[(e * 4 + 1) * 260 + tid] = w.y;
      Xs[(e * 4 + 2) * 260 + tid] = w.z;
      Xs[(e * 4 + 3) * 260 + tid] = w.w;
    }
    {
      int kw = tid >> 3, hw = (tid & 7) * 8;
      const float4* wp = (const float4*)(Wc + (size_t)(kk + kw) * HH + ht * 64 + hw);
      float4 w0 = wp[0], w1 = wp[1];
      float* d = Ws + kw * 64 + hw;
      ((float4*)d)[0] = w0; ((float4*)d)[1] = w1;
    }
    __syncthreads();
#pragma unroll 8
    for (int k = 0; k < 32; ++k) {
      float xr[4];
#pragma unroll
      for (int j = 0; j < 4; ++j) xr[j] = Xs[k * 260 + ts + 64 * j];
      const float4* wr4 = (const float4*)(Ws + k * 64 + th * 16);
#pragma unroll
      for (int i4 = 0; i4 < 4; ++i4) {
        float4 w = wr4[i4];
        float wv[4] = {w.x, w.y, w.z, w.w};
#pragma unroll
        for (int c = 0; c < 4; ++c)
#pragma unroll
          for (int j = 0; j < 4; ++j) acc[i4 * 4 + c][j] += wv[c] * xr[j];
      }
    }
    __syncthreads();
  }
#pragma unroll
  for (int i = 0; i < 16; ++i) {
    int h = ht * 64 + th * 16 + i;
    float bcv = bc[h];
    int8_t* orow = enc8 + (size_t)b * (HH * SS) + (size_t)h * SS + ts;
#pragma unroll
    for (int j = 0; j < 4; ++j) {
      float q = rintf(fminf(fmaxf((acc[i][j] + bcv) * ENC_SCALE, -127.f), 127.f));
      orow[64 * j] = (int8_t)(int)q;
    }
  }
}

// ---------------- Phase A2: G[b][j][k][q] = half( inputs[b,j,:] @ Wq[k] ) ----------------
__global__ __launch_bounds__(256) void k_G(const float* __restrict__ inputs,
                                           const float* __restrict__ Wq,
                                           __half* __restrict__ G) {
  const int qt = blockIdx.x;
  const int b  = blockIdx.y;
  const int k  = blockIdx.z;
  const int tid = threadIdx.x;
  const int ql = tid & 63, tj = tid >> 6;
  __shared__ float Xs[32 * 260];
  __shared__ float Ws[32 * 64];
  float acc[64];
#pragma unroll
  for (int j = 0; j < 64; ++j) acc[j] = 0.f;
  const int q = qt * 64 + ql;
  const float* Arow = inputs + ((size_t)b * SS + tid) * HH;
  const float* Wqk = Wq + (size_t)k * HH * QQ;
  for (int kk = 0; kk < HH; kk += 32) {
    const float4* ip = (const float4*)(Arow + kk);
#pragma unroll
    for (int e = 0; e < 8; ++e) {
      float4 w = ip[e];
      Xs[(e * 4 + 0) * 260 + tid] = w.x;
      Xs[(e * 4 + 1) * 260 + tid] = w.y;
      Xs[(e * 4 + 2) * 260 + tid] = w.z;
      Xs[(e * 4 + 3) * 260 + tid] = w.w;
    }
    {
      int hh = tid >> 3, qw = (tid & 7) * 8;
      const float* src = Wqk + (size_t)(kk + hh) * QQ;
      float* d = Ws + hh * 64 + qw;
#pragma unroll
      for (int e = 0; e < 8; ++e) {
        int qg = qt * 64 + qw + e;
        d[e] = (qg < QQ) ? src[qg] : 0.f;
      }
    }
    __syncthreads();
#pragma unroll 4
    for (int k2 = 0; k2 < 32; ++k2) {
      float wr = Ws[k2 * 64 + ql];
      const float4* xp = (const float4*)(Xs + k2 * 260 + tj * 64);
#pragma unroll
      for (int j4 = 0; j4 < 16; ++j4) {
        float4 x = xp[j4];
        acc[j4 * 4 + 0] += wr * x.x;
        acc[j4 * 4 + 1] += wr * x.y;
        acc[j4 * 4 + 2] += wr * x.z;
        acc[j4 * 4 + 3] += wr * x.w;
      }
    }
    __syncthreads();
  }
  if (q < QQ) {
#pragma unroll
    for (int j = 0; j < 64; ++j) {
      size_t jg = (size_t)b * SS + (tj * 64 + j);
      G[(jg * 3 + k) * QQ + q] = __float2half(acc[j]);
    }
  }
}

// ---------------- W2 pack: W2[qp][h] = half2(w_q[2qp][h], w_q[2qp+1][h]), qp<184 ----------------
__global__ __launch_bounds__(1024) void k_w2(const float* __restrict__ w_q,
                                             __half2* __restrict__ W2) {
  int t = blockIdx.x * 1024 + threadIdx.x;
  if (t < QP2 * HH) {
    int qp = t / HH, h = t % HH;
    float a = (2 * qp < QQ) ? w_q[(size_t)(2 * qp) * HH + h] : 0.f;
    float b = (2 * qp + 1 < QQ) ? w_q[(size_t)(2 * qp + 1) * HH + h] : 0.f;
    W2[t] = __floats2half2_rn(a, b);
  }
}

// ---------------- Main scan ----------------
// Register discipline v3 (lessons of rounds 4-8): NO long-lived per-thread
// arrays AT ALL — allocator placement (AGPR vs scratch) is roulette we lost
// 3x. enc8 is L2-resident by construction (128 KB/block, 2 MB/XCD); stream
// it EVERY STEP in two 8-load batches whose latency hides under P2 / P3-A.
// Peak transient window 16 VGPRs.
//  - P2 via v_dot2_f32_f16 on q-pair-packed W2 (23 x 16B loads, unroll 4).
//  - threefry/Gumbel + mask hoisted before b1.
//  - P4 spread over all 16 waves (4 threads/s), part padded [16][260].
__global__ __launch_bounds__(1024, 4) void k_scan(
    const __half2* __restrict__ W2, const float* __restrict__ v,
    const int8_t* __restrict__ enc8, const __half* __restrict__ G,
    float* __restrict__ out, double* __restrict__ lpb, double* __restrict__ entb) {
  const int b = blockIdx.x;
  const int tid = (int)threadIdx.x;
  const int lane = tid & 63;
  const int wid = tid >> 6;            // 16 waves
  // P2 geometry: lane = q_sub*8 + hq; q_sub 0..7 (23 q-pairs each), hq 0..7 (4 h each)
  const int q_sub = lane >> 3;
  const int hq = lane & 7;
  // P3 geometry
  const int hl = lane >> 5;            // 0..1
  const int sl = lane & 31;
  const int sbase = sl * 8;
  // P4 geometry: 4 threads per s
  const int s4 = tid >> 2;             // 0..255
  const int rq = tid & 3;              // 0..3

  __shared__ float2 evq[HH];           // .x = CC*eq[h] (per step), .y = -2*v[h]
  __shared__ __half2 q2_s[QP2];        // current query as q-pairs (relu'd), pad zeroed
  __shared__ float q12_s[QP];          // prefetched G0+G1 for next step (float)
  __shared__ float part[16][260];      // +4 pad: P4 spread reads near-conflict-free
  __shared__ float m_s[SS];
  __shared__ float mask_s[SS];
  __shared__ float4 wred[16];
  __shared__ int hist[3];
  __shared__ float Vtot_s;

  // ---- init ----
  if (tid < HH) evq[tid] = make_float2(0.f, -2.0f * v[tid]);
  if (tid < SS) mask_s[tid] = 0.f;
  if (tid < QP) q12_s[tid] = 0.f;
  if (tid < QP2) q2_s[tid] = __floats2half2_rn(0.f, 0.f);
  if (tid < 3) hist[tid] = -1;
  if (tid < 64) {
    float s = 0.f;
#pragma unroll
    for (int j = 0; j < 8; ++j) s += v[tid + 64 * j];
#pragma unroll
    for (int off = 32; off; off >>= 1) s += __shfl_xor(s, off);
    if (tid == 0) Vtot_s = s;
  }
  __syncthreads();
  const float Vtot = Vtot_s;

  // ---- per-thread enc base pointer (data streamed from L2 each step) ----
  const int8_t* encW = enc8 + (size_t)b * (HH * SS) + (size_t)(wid * 32 + hl) * SS + sbase;

  const __half* Gb = G + (size_t)b * SS * 3 * QQ;
  const __half2* wp2 = W2 + (size_t)(q_sub * 23) * HH + (wid << 5) + (hq << 2);

  double lp_acc = 0.0, ent_acc = 0.0;
  int first_idx = 0;

  for (int t = 0; t < SS; ++t) {
    // ---- enc batch A (rows 0..7 of this thread's 16): L2 latency hides under P2 ----
    uint2 encA[8];
#pragma unroll
    for (int i = 0; i < 8; ++i)
      encA[i] = *(const uint2*)(encW + (size_t)(2 * i) * SS);

    // ---- G prefetch issue (next-step q12) ----
    const int p0 = hist[1], p1 = hist[2];
    uint2 g0raw = make_uint2(0, 0), g1raw = make_uint2(0, 0);
    const bool pf = (tid < 90);
    if (pf) {
      if (p0 >= 0) g0raw = *(const uint2*)(Gb + ((size_t)p0 * 3 + 0) * QQ + 4 * tid);
      if (p1 >= 0) g1raw = *(const uint2*)(Gb + ((size_t)p1 * 3 + 1) * QQ + 4 * tid);
    }

    // ---- P2: eq over own 32-h slice; lane covers 4 h, 23 q-pairs (fdot2) ----
    {
      float a[4];
#pragma unroll
      for (int j = 0; j < 4; ++j) a[j] = 0.f;
      const __half2* qsp = q2_s + q_sub * 23;
#pragma unroll 4
      for (int i = 0; i < 23; ++i) {
        uint4 raw = *(const uint4*)(wp2 + (size_t)i * HH);   // 4 half2 (4 h, 1 q-pair)
        __half2 qv = qsp[i];
#if __has_builtin(__builtin_amdgcn_fdot2)
        f16x2 qf = *(f16x2*)&qv;
        a[0] = __builtin_amdgcn_fdot2(qf, *(f16x2*)&raw.x, a[0], false);
        a[1] = __builtin_amdgcn_fdot2(qf, *(f16x2*)&raw.y, a[1], false);
        a[2] = __builtin_amdgcn_fdot2(qf, *(f16x2*)&raw.z, a[2], false);
        a[3] = __builtin_amdgcn_fdot2(qf, *(f16x2*)&raw.w, a[3], false);
#else
        float2 qf = __half22float2(qv);
        float2 w0 = __half22float2(*(const __half2*)&raw.x);
        float2 w1 = __half22float2(*(const __half2*)&raw.y);
        float2 w2 = __half22float2(*(const __half2*)&raw.z);
        float2 w3 = __half22float2(*(const __half2*)&raw.w);
        a[0] = fmaf(qf.x, w0.x, fmaf(qf.y, w0.y, a[0]));
        a[1] = fmaf(qf.x, w1.x, fmaf(qf.y, w1.y, a[1]));
        a[2] = fmaf(qf.x, w2.x, fmaf(qf.y, w2.y, a[2]));
        a[3] = fmaf(qf.x, w3.x, fmaf(qf.y, w3.y, a[3]));
#endif
      }
#pragma unroll
      for (int off = 8; off <= 32; off <<= 1)
#pragma unroll
        for (int j = 0; j < 4; ++j) a[j] += __shfl_xor(a[j], off);
      if (lane < 8) {        // q_sub==0, hq==lane
        int h0 = (wid << 5) + (lane << 2);
        evq[h0 + 0].x = CC * a[0];
        evq[h0 + 1].x = CC * a[1];
        evq[h0 + 2].x = CC * a[2];
        evq[h0 + 3].x = CC * a[3];
      }
      // no barrier: each wave reads only its own evq slice (in-wave ordering)
    }

    // ---- P3: scores; batch B issued first, hides under batch-A compute ----
    {
      uint2 encB[8];
#pragma unroll
      for (int i = 0; i < 8; ++i)
        encB[i] = *(const uint2*)(encW + (size_t)(16 + 2 * i) * SS);

      float acc[8];
#pragma unroll
      for (int j = 0; j < 8; ++j) acc[j] = 0.f;
#pragma unroll
      for (int i = 0; i < 16; ++i) {
        float2 ev = evq[(wid << 5) + 2 * i + hl];
        const float eqC = ev.x, mv = ev.y;
        const uint32_t w0 = (i < 8) ? encA[i].x : encB[i - 8].x;
        const uint32_t w1 = (i < 8) ? encA[i].y : encB[i - 8].y;
#pragma unroll
        for (int k = 0; k < 4; ++k) {
          {
            float f = (float)(int)(int8_t)(w0 >> (8 * k));
            float e = EXP2F(fmaf(f, ENC_INV, eqC));
            acc[k] = fmaf(mv, frcp(e + 1.0f), acc[k]);
          }
          {
            float f = (float)(int)(int8_t)(w1 >> (8 * k));
            float e = EXP2F(fmaf(f, ENC_INV, eqC));
            acc[4 + k] = fmaf(mv, frcp(e + 1.0f), acc[4 + k]);
          }
        }
      }
#pragma unroll
      for (int j = 0; j < 8; ++j) acc[j] += __shfl_xor(acc[j], 32);
      if (hl == 0) {
        *(float4*)&part[wid][sbase]     = make_float4(acc[0], acc[1], acc[2], acc[3]);
        *(float4*)&part[wid][sbase + 4] = make_float4(acc[4], acc[5], acc[6], acc[7]);
      }
    }

    // ---- consume q12 prefetch ----
    if (pf) {
      float2 f0a = __half22float2(*(const __half2*)&g0raw.x);
      float2 f0b = __half22float2(*(const __half2*)&g0raw.y);
      float2 f1a = __half22float2(*(const __half2*)&g1raw.x);
      float2 f1b = __half22float2(*(const __half2*)&g1raw.y);
      float4 qv;
      qv.x = f0a.x + f1a.x; qv.y = f0a.y + f1a.y;
      qv.z = f0b.x + f1b.x; qv.w = f0b.y + f1b.y;
      *(float4*)&q12_s[4 * tid] = qv;
    }

    // ---- gumbel + mask for P4 (2 regs live across b1 only) ----
    float gum, maskv;
    {
      TF2 o = threefry(c_keys.sk[t][0], c_keys.sk[t][1], 0u, (uint32_t)(b * SS + s4));
      float fb = __uint_as_float((o.b >> 9) | 0x3f800000u) - 1.0f;
      fb = fmaxf(fb, 1.0e-12f);
      gum = -__logf(-__logf(fb));
      maskv = mask_s[s4];
    }
    __syncthreads();   // b1: part, q12 ready

    // ================== P4: all 16 waves, 4 threads per s ==================
    {
      float a = part[rq * 4 + 0][s4];
      a += part[rq * 4 + 1][s4];
      a += part[rq * 4 + 2][s4];
      a += part[rq * 4 + 3][s4];
      a += __shfl_xor(a, 1);
      a += __shfl_xor(a, 2);          // all 4 rq lanes: full 16-row sum
      float sc = Vtot + a;
      float logit = 10.0f * fast_tanh(sc);
      float m = (maskv != 0.f) ? -1.0e8f : logit;
      if (rq == 0) m_s[s4] = m;
      float z = m + gum;
      float e = __expf(m);            // masked -> exactly 0
      float em = e * m;
      int si = s4;
#pragma unroll
      for (int off = 4; off <= 32; off <<= 1) {
        float zo = __shfl_xor(z, off);
        int io = __shfl_xor(si, off);
        if (zo > z || (zo == z && io < si)) { z = zo; si = io; }
        e += __shfl_xor(e, off);
        em += __shfl_xor(em, off);
      }
      if (lane == 0) wred[wid] = make_float4(z, __int_as_float(si), e, em);
    }
    __syncthreads();   // b2: wred, m_s ready

    // ================== finalize (all threads) + next-q build ==================
    {
      float4 r0 = wred[0];
      float z = r0.x; int si = __float_as_int(r0.y);
      float se = r0.z, sem = r0.w;
#pragma unroll
      for (int r = 1; r < 16; ++r) {
        float4 rv = wred[r];
        int io = __float_as_int(rv.y);
        if (rv.x > z || (rv.x == z && io < si)) { z = rv.x; si = io; }
        se += rv.z; sem += rv.w;
      }
      const int idx = si;
      if (pf) {   // tid < 90: q = relu(q12 + G2[idx]) -> q2_s half2 pairs
        uint2 g2 = *(const uint2*)(Gb + ((size_t)idx * 3 + 2) * QQ + 4 * tid);
        float2 f2a = __half22float2(*(const __half2*)&g2.x);
        float2 f2b = __half22float2(*(const __half2*)&g2.y);
        float4 q12v = *(const float4*)&q12_s[4 * tid];
        float4 qn;
        qn.x = fmaxf(q12v.x + f2a.x, 0.f);
        qn.y = fmaxf(q12v.y + f2a.y, 0.f);
        qn.z = fmaxf(q12v.z + f2b.x, 0.f);
        qn.w = fmaxf(q12v.w + f2b.y, 0.f);
        q2_s[2 * tid]     = __floats2half2_rn(qn.x, qn.y);
        q2_s[2 * tid + 1] = __floats2half2_rn(qn.z, qn.w);
      }
      if (tid == 0) {
        float lse = __logf(se);
        float mi = m_s[idx];
        lp_acc += (double)(mi - lse);
        ent_acc += (double)(lse - sem / se);
        out[b * 257 + t] = (float)idx;
        mask_s[idx] = 1.0f;
        hist[0] = hist[1]; hist[1] = hist[2]; hist[2] = idx;
        if (t == 0) first_idx = idx;
      }
    }
    __syncthreads();   // b3: q2_s, hist, mask updated
  }

  if (tid == 0) {
    out[b * 257 + 256] = (float)first_idx;
    lpb[b] = lp_acc;
    entb[b] = ent_acc;
  }
}

// ---------------- Final deterministic reduction ----------------
__global__ void k_final(const double* __restrict__ lpb,
                        const double* __restrict__ entb, float* __restrict__ out) {
  if (threadIdx.x == 0) {
    double a = 0.0, c = 0.0;
    for (int i = 0; i < BB; ++i) { a += lpb[i]; c += entb[i]; }
    out[BB * 257 + 0] = (float)a;
    out[BB * 257 + 1] = (float)c;
  }
}

extern "C" void kernel_launch(void* const* d_in, const int* in_sizes, int n_in,
                              void* d_out, int out_size, void* d_ws, size_t ws_size,
                              hipStream_t stream) {
  const float* inputs = (const float*)d_in[0];
  const float* Wc  = (const float*)d_in[1];
  const float* bc  = (const float*)d_in[2];
  const float* Wq  = (const float*)d_in[3];
  const float* w_q = (const float*)d_in[4];
  const float* v   = (const float*)d_in[5];
  float* out = (float*)d_out;

  char* ws = (char*)d_ws;
  const size_t encBytes = (size_t)BB * HH * SS;            // 16.8 MB int8
  const size_t gBytes   = (size_t)3 * BB * SS * QQ * 2;    // 70.8 MB fp16
  const size_t w2Bytes  = (size_t)QP2 * HH * 4;            // 377 KB half2 (q-pair packed)
  int8_t* enc8 = (int8_t*)ws;
  __half* G   = (__half*)(ws + encBytes);
  __half2* W2 = (__half2*)(ws + encBytes + gBytes);
  size_t goff = (encBytes + gBytes + w2Bytes + 1023) & ~(size_t)1023;
  double* lpb = (double*)(ws + goff);
  double* entb = lpb + BB;

  dim3 gA1(8, BB);
  k_enc<<<gA1, 256, 0, stream>>>(inputs, Wc, bc, enc8);
  dim3 gA2(6, BB, 3);
  k_G<<<gA2, 256, 0, stream>>>(inputs, Wq, G);
  k_w2<<<(QP2 * HH + 1023) / 1024, 1024, 0, stream>>>(w_q, W2);
  k_scan<<<BB, 1024, 0, stream>>>(W2, v, enc8, G, out, lpb, entb);
  k_final<<<1, 64, 0, stream>>>(lpb, entb, out);
}

// Round 10
// 4807.677 us; speedup vs baseline: 3.5548x; 1.6688x over previous
//
#include <hip/hip_runtime.h>
#include <hip/hip_fp16.h>
#include <stdint.h>

#define BB 128
#define SS 256
#define HH 512
#define QQ 360
#define QP 368    // padded q, pad zeroed
#define QP2 184   // q-pairs

// ---------------- Threefry-2x32 (JAX semantics) ----------------
struct TF2 { uint32_t a, b; };

__host__ __device__ constexpr uint32_t rotl32(uint32_t x, int d) {
  return (x << d) | (x >> (32 - d));
}

__host__ __device__ constexpr TF2 threefry(uint32_t k0, uint32_t k1,
                                           uint32_t x0, uint32_t x1) {
  uint32_t ks[3] = {k0, k1, k0 ^ k1 ^ 0x1BD11BDAu};
  x0 += ks[0]; x1 += ks[1];
  const int R0[4] = {13, 15, 26, 6};
  const int R1[4] = {17, 29, 16, 24};
  for (int g = 0; g < 5; ++g) {
    const int* r = (g & 1) ? R1 : R0;
    for (int i = 0; i < 4; ++i) { x0 += x1; x1 = rotl32(x1, r[i]); x1 ^= x0; }
    x0 += ks[(g + 1) % 3];
    x1 += ks[(g + 2) % 3] + (uint32_t)(g + 1);
  }
  return TF2{x0, x1};
}

struct KeyTab { uint32_t sk[256][2]; };
constexpr KeyTab make_keys() {
  KeyTab K{};
  uint32_t k0 = 0u, k1 = 1u;
  for (int t = 0; t < 256; ++t) {
    TF2 nk = threefry(k0, k1, 0u, 0u);
    TF2 sk = threefry(k0, k1, 0u, 1u);
    K.sk[t][0] = sk.a; K.sk[t][1] = sk.b;
    k0 = nk.a; k1 = nk.b;
  }
  return K;
}
__constant__ KeyTab c_keys = make_keys();

// ---------------- fast math helpers ----------------
__device__ __forceinline__ float frcp(float x) {
#if __has_builtin(__builtin_amdgcn_rcpf)
  return __builtin_amdgcn_rcpf(x);
#else
  return 1.0f / x;
#endif
}

#if __has_builtin(__builtin_amdgcn_exp2f)
  #define EXP2F(x) __builtin_amdgcn_exp2f(x)
  #define CC 2.8853900817779268f
#else
  #define EXP2F(x) __expf(x)
  #define CC 2.0f
#endif

#define ENC_SCALE 21.0f
#define ENC_INV (CC / ENC_SCALE)

__device__ __forceinline__ float fast_tanh(float x) {
  float e = __expf(2.0f * x);
  return 1.0f - 2.0f * frcp(e + 1.0f);
}

typedef _Float16 f16x2 __attribute__((ext_vector_type(2)));

// ---------------- Phase A1: enc8[b][h][s] = int8( 21 * (inputs @ Wc + bc)^T ) ----------------
__global__ __launch_bounds__(256) void k_enc(const float* __restrict__ inputs,
                                             const float* __restrict__ Wc,
                                             const float* __restrict__ bc,
                                             int8_t* __restrict__ enc8) {
  const int ht = blockIdx.x;
  const int b  = blockIdx.y;
  const int tid = threadIdx.x;
  const int ts = tid & 63, th = tid >> 6;
  __shared__ float Xs[32 * 260];
  __shared__ float Ws[32 * 64];
  float acc[16][4];
#pragma unroll
  for (int i = 0; i < 16; ++i)
#pragma unroll
    for (int j = 0; j < 4; ++j) acc[i][j] = 0.f;

  const float* Arow = inputs + ((size_t)b * SS + tid) * HH;
  for (int kk = 0; kk < HH; kk += 32) {
    const float4* ip = (const float4*)(Arow + kk);
#pragma unroll
    for (int e = 0; e < 8; ++e) {
      float4 w = ip[e];
      Xs[(e * 4 + 0) * 260 + tid] = w.x;
      Xs[(e * 4 + 1) * 260 + tid] = w.y;
      Xs[(e * 4 + 2) * 260 + tid] = w.z;
      Xs[(e * 4 + 3) * 260 + tid] = w.w;
    }
    {
      int kw = tid >> 3, hw = (tid & 7) * 8;
      const float4* wp = (const float4*)(Wc + (size_t)(kk + kw) * HH + ht * 64 + hw);
      float4 w0 = wp[0], w1 = wp[1];
      float* d = Ws + kw * 64 + hw;
      ((float4*)d)[0] = w0; ((float4*)d)[1] = w1;
    }
    __syncthreads();
#pragma unroll 8
    for (int k = 0; k < 32; ++k) {
      float xr[4];
#pragma unroll
      for (int j = 0; j < 4; ++j) xr[j] = Xs[k * 260 + ts + 64 * j];
      const float4* wr4 = (const float4*)(Ws + k * 64 + th * 16);
#pragma unroll
      for (int i4 = 0; i4 < 4; ++i4) {
        float4 w = wr4[i4];
        float wv[4] = {w.x, w.y, w.z, w.w};
#pragma unroll
        for (int c = 0; c < 4; ++c)
#pragma unroll
          for (int j = 0; j < 4; ++j) acc[i4 * 4 + c][j] += wv[c] * xr[j];
      }
    }
    __syncthreads();
  }
#pragma unroll
  for (int i = 0; i < 16; ++i) {
    int h = ht * 64 + th * 16 + i;
    float bcv = bc[h];
    int8_t* orow = enc8 + (size_t)b * (HH * SS) + (size_t)h * SS + ts;
#pragma unroll
    for (int j = 0; j < 4; ++j) {
      float q = rintf(fminf(fmaxf((acc[i][j] + bcv) * ENC_SCALE, -127.f), 127.f));
      orow[64 * j] = (int8_t)(int)q;
    }
  }
}

// ---------------- Phase A2: G[b][j][k][q] = half( inputs[b,j,:] @ Wq[k] ) ----------------
__global__ __launch_bounds__(256) void k_G(const float* __restrict__ inputs,
                                           const float* __restrict__ Wq,
                                           __half* __restrict__ G) {
  const int qt = blockIdx.x;
  const int b  = blockIdx.y;
  const int k  = blockIdx.z;
  const int tid = threadIdx.x;
  const int ql = tid & 63, tj = tid >> 6;
  __shared__ float Xs[32 * 260];
  __shared__ float Ws[32 * 64];
  float acc[64];
#pragma unroll
  for (int j = 0; j < 64; ++j) acc[j] = 0.f;
  const int q = qt * 64 + ql;
  const float* Arow = inputs + ((size_t)b * SS + tid) * HH;
  const float* Wqk = Wq + (size_t)k * HH * QQ;
  for (int kk = 0; kk < HH; kk += 32) {
    const float4* ip = (const float4*)(Arow + kk);
#pragma unroll
    for (int e = 0; e < 8; ++e) {
      float4 w = ip[e];
      Xs[(e * 4 + 0) * 260 + tid] = w.x;
      Xs[(e * 4 + 1) * 260 + tid] = w.y;
      Xs[(e * 4 + 2) * 260 + tid] = w.z;
      Xs[(e * 4 + 3) * 260 + tid] = w.w;
    }
    {
      int hh = tid >> 3, qw = (tid & 7) * 8;
      const float* src = Wqk + (size_t)(kk + hh) * QQ;
      float* d = Ws + hh * 64 + qw;
#pragma unroll
      for (int e = 0; e < 8; ++e) {
        int qg = qt * 64 + qw + e;
        d[e] = (qg < QQ) ? src[qg] : 0.f;
      }
    }
    __syncthreads();
#pragma unroll 4
    for (int k2 = 0; k2 < 32; ++k2) {
      float wr = Ws[k2 * 64 + ql];
      const float4* xp = (const float4*)(Xs + k2 * 260 + tj * 64);
#pragma unroll
      for (int j4 = 0; j4 < 16; ++j4) {
        float4 x = xp[j4];
        acc[j4 * 4 + 0] += wr * x.x;
        acc[j4 * 4 + 1] += wr * x.y;
        acc[j4 * 4 + 2] += wr * x.z;
        acc[j4 * 4 + 3] += wr * x.w;
      }
    }
    __syncthreads();
  }
  if (q < QQ) {
#pragma unroll
    for (int j = 0; j < 64; ++j) {
      size_t jg = (size_t)b * SS + (tj * 64 + j);
      G[(jg * 3 + k) * QQ + q] = __float2half(acc[j]);
    }
  }
}

// ---------------- W2 pack: W2[qp][h] = half2(w_q[2qp][h], w_q[2qp+1][h]), qp<184 ----------------
__global__ __launch_bounds__(1024) void k_w2(const float* __restrict__ w_q,
                                             __half2* __restrict__ W2) {
  int t = blockIdx.x * 1024 + threadIdx.x;
  if (t < QP2 * HH) {
    int qp = t / HH, h = t % HH;
    float a = (2 * qp < QQ) ? w_q[(size_t)(2 * qp) * HH + h] : 0.f;
    float b = (2 * qp + 1 < QQ) ? w_q[(size_t)(2 * qp + 1) * HH + h] : 0.f;
    W2[t] = __floats2half2_rn(a, b);
  }
}

// ---------------- Main scan ----------------
// enc home v4: registers = allocator roulette (lost rounds 4/6/8), L2 = 6.3 GB
// thrash (rounds 8/9 identical counters). LDS is the only deterministic on-CU
// store: 128 KB enc + 25 KB existing = 156 KB of the 160 KB/CU, 1 block/CU.
// Copied once at init; P3 reads uint2 from LDS (4-way b64 bank conflict on the
// hl halves — ~1.6x on the LDS pipe per m136, negligible vs HBM stalls).
//  - P2 via v_dot2_f32_f16 on q-pair-packed W2 (23 x 16B loads, unroll 4).
//  - threefry/Gumbel + mask hoisted before b1.
//  - P4 spread over all 16 waves (4 threads/s), part padded [16][260].
__global__ __launch_bounds__(1024, 4) void k_scan(
    const __half2* __restrict__ W2, const float* __restrict__ v,
    const int8_t* __restrict__ enc8, const __half* __restrict__ G,
    float* __restrict__ out, double* __restrict__ lpb, double* __restrict__ entb) {
  const int b = blockIdx.x;
  const int tid = (int)threadIdx.x;
  const int lane = tid & 63;
  const int wid = tid >> 6;            // 16 waves
  // P2 geometry: lane = q_sub*8 + hq; q_sub 0..7 (23 q-pairs each), hq 0..7 (4 h each)
  const int q_sub = lane >> 3;
  const int hq = lane & 7;
  // P3 geometry
  const int hl = lane >> 5;            // 0..1
  const int sl = lane & 31;
  const int sbase = sl * 8;
  // P4 geometry: 4 threads per s
  const int s4 = tid >> 2;             // 0..255
  const int rq = tid & 3;              // 0..3

  __shared__ uint2 enc_lds[HH * 32];   // 131072 B: enc8[b] linear, uint2[h][sl]
  __shared__ float2 evq[HH];           // .x = CC*eq[h] (per step), .y = -2*v[h]
  __shared__ __half2 q2_s[QP2];        // current query as q-pairs (relu'd), pad zeroed
  __shared__ float q12_s[QP];          // prefetched G0+G1 for next step (float)
  __shared__ float part[16][260];      // +4 pad: P4 spread reads near-conflict-free
  __shared__ float m_s[SS];
  __shared__ float mask_s[SS];
  __shared__ float4 wred[16];
  __shared__ int hist[3];
  __shared__ float Vtot_s;

  // ---- init ----
  if (tid < HH) evq[tid] = make_float2(0.f, -2.0f * v[tid]);
  if (tid < SS) mask_s[tid] = 0.f;
  if (tid < QP) q12_s[tid] = 0.f;
  if (tid < QP2) q2_s[tid] = __floats2half2_rn(0.f, 0.f);
  if (tid < 3) hist[tid] = -1;
  if (tid < 64) {
    float s = 0.f;
#pragma unroll
    for (int j = 0; j < 8; ++j) s += v[tid + 64 * j];
#pragma unroll
    for (int off = 32; off; off >>= 1) s += __shfl_xor(s, off);
    if (tid == 0) Vtot_s = s;
  }
  // ---- enc8[b] -> LDS, once (16B granules, coalesced) ----
  {
    const uint4* src = (const uint4*)(enc8 + (size_t)b * (HH * SS));
    uint4* dst = (uint4*)enc_lds;
#pragma unroll
    for (int it = 0; it < 8; ++it)
      dst[it * 1024 + tid] = src[it * 1024 + tid];
  }
  __syncthreads();
  const float Vtot = Vtot_s;

  const __half* Gb = G + (size_t)b * SS * 3 * QQ;
  const __half2* wp2 = W2 + (size_t)(q_sub * 23) * HH + (wid << 5) + (hq << 2);
  // this thread's enc rows: (wid*32 + 2i + hl), s-slot sl
  const uint2* encL = enc_lds + ((size_t)(wid * 32 + hl) * 32) + sl;

  double lp_acc = 0.0, ent_acc = 0.0;
  int first_idx = 0;

  for (int t = 0; t < SS; ++t) {
    // ---- G prefetch issue (next-step q12) ----
    const int p0 = hist[1], p1 = hist[2];
    uint2 g0raw = make_uint2(0, 0), g1raw = make_uint2(0, 0);
    const bool pf = (tid < 90);
    if (pf) {
      if (p0 >= 0) g0raw = *(const uint2*)(Gb + ((size_t)p0 * 3 + 0) * QQ + 4 * tid);
      if (p1 >= 0) g1raw = *(const uint2*)(Gb + ((size_t)p1 * 3 + 1) * QQ + 4 * tid);
    }

    // ---- P2: eq over own 32-h slice; lane covers 4 h, 23 q-pairs (fdot2) ----
    {
      float a[4];
#pragma unroll
      for (int j = 0; j < 4; ++j) a[j] = 0.f;
      const __half2* qsp = q2_s + q_sub * 23;
#pragma unroll 4
      for (int i = 0; i < 23; ++i) {
        uint4 raw = *(const uint4*)(wp2 + (size_t)i * HH);   // 4 half2 (4 h, 1 q-pair)
        __half2 qv = qsp[i];
#if __has_builtin(__builtin_amdgcn_fdot2)
        f16x2 qf = *(f16x2*)&qv;
        a[0] = __builtin_amdgcn_fdot2(qf, *(f16x2*)&raw.x, a[0], false);
        a[1] = __builtin_amdgcn_fdot2(qf, *(f16x2*)&raw.y, a[1], false);
        a[2] = __builtin_amdgcn_fdot2(qf, *(f16x2*)&raw.z, a[2], false);
        a[3] = __builtin_amdgcn_fdot2(qf, *(f16x2*)&raw.w, a[3], false);
#else
        float2 qf = __half22float2(qv);
        float2 w0 = __half22float2(*(const __half2*)&raw.x);
        float2 w1 = __half22float2(*(const __half2*)&raw.y);
        float2 w2 = __half22float2(*(const __half2*)&raw.z);
        float2 w3 = __half22float2(*(const __half2*)&raw.w);
        a[0] = fmaf(qf.x, w0.x, fmaf(qf.y, w0.y, a[0]));
        a[1] = fmaf(qf.x, w1.x, fmaf(qf.y, w1.y, a[1]));
        a[2] = fmaf(qf.x, w2.x, fmaf(qf.y, w2.y, a[2]));
        a[3] = fmaf(qf.x, w3.x, fmaf(qf.y, w3.y, a[3]));
#endif
      }
#pragma unroll
      for (int off = 8; off <= 32; off <<= 1)
#pragma unroll
        for (int j = 0; j < 4; ++j) a[j] += __shfl_xor(a[j], off);
      if (lane < 8) {        // q_sub==0, hq==lane
        int h0 = (wid << 5) + (lane << 2);
        evq[h0 + 0].x = CC * a[0];
        evq[h0 + 1].x = CC * a[1];
        evq[h0 + 2].x = CC * a[2];
        evq[h0 + 3].x = CC * a[3];
      }
      // no barrier: each wave reads only its own evq slice (in-wave ordering)
    }

    // ---- P3: scores; enc from LDS ----
    {
      float acc[8];
#pragma unroll
      for (int j = 0; j < 8; ++j) acc[j] = 0.f;
#pragma unroll
      for (int i = 0; i < 16; ++i) {
        float2 ev = evq[(wid << 5) + 2 * i + hl];
        const float eqC = ev.x, mv = ev.y;
        uint2 w = encL[(size_t)(2 * i) * 32];
        const uint32_t w0 = w.x, w1 = w.y;
#pragma unroll
        for (int k = 0; k < 4; ++k) {
          {
            float f = (float)(int)(int8_t)(w0 >> (8 * k));
            float e = EXP2F(fmaf(f, ENC_INV, eqC));
            acc[k] = fmaf(mv, frcp(e + 1.0f), acc[k]);
          }
          {
            float f = (float)(int)(int8_t)(w1 >> (8 * k));
            float e = EXP2F(fmaf(f, ENC_INV, eqC));
            acc[4 + k] = fmaf(mv, frcp(e + 1.0f), acc[4 + k]);
          }
        }
      }
#pragma unroll
      for (int j = 0; j < 8; ++j) acc[j] += __shfl_xor(acc[j], 32);
      if (hl == 0) {
        *(float4*)&part[wid][sbase]     = make_float4(acc[0], acc[1], acc[2], acc[3]);
        *(float4*)&part[wid][sbase + 4] = make_float4(acc[4], acc[5], acc[6], acc[7]);
      }
    }

    // ---- consume q12 prefetch ----
    if (pf) {
      float2 f0a = __half22float2(*(const __half2*)&g0raw.x);
      float2 f0b = __half22float2(*(const __half2*)&g0raw.y);
      float2 f1a = __half22float2(*(const __half2*)&g1raw.x);
      float2 f1b = __half22float2(*(const __half2*)&g1raw.y);
      float4 qv;
      qv.x = f0a.x + f1a.x; qv.y = f0a.y + f1a.y;
      qv.z = f0b.x + f1b.x; qv.w = f0b.y + f1b.y;
      *(float4*)&q12_s[4 * tid] = qv;
    }

    // ---- gumbel + mask for P4 (2 regs live across b1 only) ----
    float gum, maskv;
    {
      TF2 o = threefry(c_keys.sk[t][0], c_keys.sk[t][1], 0u, (uint32_t)(b * SS + s4));
      float fb = __uint_as_float((o.b >> 9) | 0x3f800000u) - 1.0f;
      fb = fmaxf(fb, 1.0e-12f);
      gum = -__logf(-__logf(fb));
      maskv = mask_s[s4];
    }
    __syncthreads();   // b1: part, q12 ready

    // ================== P4: all 16 waves, 4 threads per s ==================
    {
      float a = part[rq * 4 + 0][s4];
      a += part[rq * 4 + 1][s4];
      a += part[rq * 4 + 2][s4];
      a += part[rq * 4 + 3][s4];
      a += __shfl_xor(a, 1);
      a += __shfl_xor(a, 2);          // all 4 rq lanes: full 16-row sum
      float sc = Vtot + a;
      float logit = 10.0f * fast_tanh(sc);
      float m = (maskv != 0.f) ? -1.0e8f : logit;
      if (rq == 0) m_s[s4] = m;
      float z = m + gum;
      float e = __expf(m);            // masked -> exactly 0
      float em = e * m;
      int si = s4;
#pragma unroll
      for (int off = 4; off <= 32; off <<= 1) {
        float zo = __shfl_xor(z, off);
        int io = __shfl_xor(si, off);
        if (zo > z || (zo == z && io < si)) { z = zo; si = io; }
        e += __shfl_xor(e, off);
        em += __shfl_xor(em, off);
      }
      if (lane == 0) wred[wid] = make_float4(z, __int_as_float(si), e, em);
    }
    __syncthreads();   // b2: wred, m_s ready

    // ================== finalize (all threads) + next-q build ==================
    {
      float4 r0 = wred[0];
      float z = r0.x; int si = __float_as_int(r0.y);
      float se = r0.z, sem = r0.w;
#pragma unroll
      for (int r = 1; r < 16; ++r) {
        float4 rv = wred[r];
        int io = __float_as_int(rv.y);
        if (rv.x > z || (rv.x == z && io < si)) { z = rv.x; si = io; }
        se += rv.z; sem += rv.w;
      }
      const int idx = si;
      if (pf) {   // tid < 90: q = relu(q12 + G2[idx]) -> q2_s half2 pairs
        uint2 g2 = *(const uint2*)(Gb + ((size_t)idx * 3 + 2) * QQ + 4 * tid);
        float2 f2a = __half22float2(*(const __half2*)&g2.x);
        float2 f2b = __half22float2(*(const __half2*)&g2.y);
        float4 q12v = *(const float4*)&q12_s[4 * tid];
        float4 qn;
        qn.x = fmaxf(q12v.x + f2a.x, 0.f);
        qn.y = fmaxf(q12v.y + f2a.y, 0.f);
        qn.z = fmaxf(q12v.z + f2b.x, 0.f);
        qn.w = fmaxf(q12v.w + f2b.y, 0.f);
        q2_s[2 * tid]     = __floats2half2_rn(qn.x, qn.y);
        q2_s[2 * tid + 1] = __floats2half2_rn(qn.z, qn.w);
      }
      if (tid == 0) {
        float lse = __logf(se);
        float mi = m_s[idx];
        lp_acc += (double)(mi - lse);
        ent_acc += (double)(lse - sem / se);
        out[b * 257 + t] = (float)idx;
        mask_s[idx] = 1.0f;
        hist[0] = hist[1]; hist[1] = hist[2]; hist[2] = idx;
        if (t == 0) first_idx = idx;
      }
    }
    __syncthreads();   // b3: q2_s, hist, mask updated
  }

  if (tid == 0) {
    out[b * 257 + 256] = (float)first_idx;
    lpb[b] = lp_acc;
    entb[b] = ent_acc;
  }
}

// ---------------- Final deterministic reduction ----------------
__global__ void k_final(const double* __restrict__ lpb,
                        const double* __restrict__ entb, float* __restrict__ out) {
  if (threadIdx.x == 0) {
    double a = 0.0, c = 0.0;
    for (int i = 0; i < BB; ++i) { a += lpb[i]; c += entb[i]; }
    out[BB * 257 + 0] = (float)a;
    out[BB * 257 + 1] = (float)c;
  }
}

extern "C" void kernel_launch(void* const* d_in, const int* in_sizes, int n_in,
                              void* d_out, int out_size, void* d_ws, size_t ws_size,
                              hipStream_t stream) {
  const float* inputs = (const float*)d_in[0];
  const float* Wc  = (const float*)d_in[1];
  const float* bc  = (const float*)d_in[2];
  const float* Wq  = (const float*)d_in[3];
  const float* w_q = (const float*)d_in[4];
  const float* v   = (const float*)d_in[5];
  float* out = (float*)d_out;

  char* ws = (char*)d_ws;
  const size_t encBytes = (size_t)BB * HH * SS;            // 16.8 MB int8
  const size_t gBytes   = (size_t)3 * BB * SS * QQ * 2;    // 70.8 MB fp16
  const size_t w2Bytes  = (size_t)QP2 * HH * 4;            // 377 KB half2 (q-pair packed)
  int8_t* enc8 = (int8_t*)ws;
  __half* G   = (__half*)(ws + encBytes);
  __half2* W2 = (__half2*)(ws + encBytes + gBytes);
  size_t goff = (encBytes + gBytes + w2Bytes + 1023) & ~(size_t)1023;
  double* lpb = (double*)(ws + goff);
  double* entb = lpb + BB;

  dim3 gA1(8, BB);
  k_enc<<<gA1, 256, 0, stream>>>(inputs, Wc, bc, enc8);
  dim3 gA2(6, BB, 3);
  k_G<<<gA2, 256, 0, stream>>>(inputs, Wq, G);
  k_w2<<<(QP2 * HH + 1023) / 1024, 1024, 0, stream>>>(w_q, W2);
  k_scan<<<BB, 1024, 0, stream>>>(W2, v, enc8, G, out, lpb, entb);
  k_final<<<1, 64, 0, stream>>>(lpb, entb, out);
}

// Round 11
// 4701.958 us; speedup vs baseline: 3.6348x; 1.0225x over previous
//
#include <hip/hip_runtime.h>
#include <hip/hip_fp16.h>
#include <stdint.h>

#define BB 128
#define SS 256
#define HH 512
#define QQ 360
#define QP 368    // padded q, pad zeroed
#define QP2 184   // q-pairs

// ---------------- Threefry-2x32 (JAX semantics) ----------------
struct TF2 { uint32_t a, b; };

__host__ __device__ constexpr uint32_t rotl32(uint32_t x, int d) {
  return (x << d) | (x >> (32 - d));
}

__host__ __device__ constexpr TF2 threefry(uint32_t k0, uint32_t k1,
                                           uint32_t x0, uint32_t x1) {
  uint32_t ks[3] = {k0, k1, k0 ^ k1 ^ 0x1BD11BDAu};
  x0 += ks[0]; x1 += ks[1];
  const int R0[4] = {13, 15, 26, 6};
  const int R1[4] = {17, 29, 16, 24};
  for (int g = 0; g < 5; ++g) {
    const int* r = (g & 1) ? R1 : R0;
    for (int i = 0; i < 4; ++i) { x0 += x1; x1 = rotl32(x1, r[i]); x1 ^= x0; }
    x0 += ks[(g + 1) % 3];
    x1 += ks[(g + 2) % 3] + (uint32_t)(g + 1);
  }
  return TF2{x0, x1};
}

struct KeyTab { uint32_t sk[256][2]; };
constexpr KeyTab make_keys() {
  KeyTab K{};
  uint32_t k0 = 0u, k1 = 1u;
  for (int t = 0; t < 256; ++t) {
    TF2 nk = threefry(k0, k1, 0u, 0u);
    TF2 sk = threefry(k0, k1, 0u, 1u);
    K.sk[t][0] = sk.a; K.sk[t][1] = sk.b;
    k0 = nk.a; k1 = nk.b;
  }
  return K;
}
__constant__ KeyTab c_keys = make_keys();

// ---------------- fast math helpers ----------------
__device__ __forceinline__ float frcp(float x) {
#if __has_builtin(__builtin_amdgcn_rcpf)
  return __builtin_amdgcn_rcpf(x);
#else
  return 1.0f / x;
#endif
}

#if __has_builtin(__builtin_amdgcn_exp2f)
  #define EXP2F(x) __builtin_amdgcn_exp2f(x)
  #define CC 2.8853900817779268f
#else
  #define EXP2F(x) __expf(x)
  #define CC 2.0f
#endif

#define ENC_SCALE 21.0f
#define ENC_INV (CC / ENC_SCALE)

__device__ __forceinline__ float fast_tanh(float x) {
  float e = __expf(2.0f * x);
  return 1.0f - 2.0f * frcp(e + 1.0f);
}

typedef _Float16 f16x2 __attribute__((ext_vector_type(2)));

// ---------------- Phase A1: enc8[b][h][s] = int8( 21 * (inputs @ Wc + bc)^T ) ----------------
__global__ __launch_bounds__(256) void k_enc(const float* __restrict__ inputs,
                                             const float* __restrict__ Wc,
                                             const float* __restrict__ bc,
                                             int8_t* __restrict__ enc8) {
  const int ht = blockIdx.x;
  const int b  = blockIdx.y;
  const int tid = threadIdx.x;
  const int ts = tid & 63, th = tid >> 6;
  __shared__ float Xs[32 * 260];
  __shared__ float Ws[32 * 64];
  float acc[16][4];
#pragma unroll
  for (int i = 0; i < 16; ++i)
#pragma unroll
    for (int j = 0; j < 4; ++j) acc[i][j] = 0.f;

  const float* Arow = inputs + ((size_t)b * SS + tid) * HH;
  for (int kk = 0; kk < HH; kk += 32) {
    const float4* ip = (const float4*)(Arow + kk);
#pragma unroll
    for (int e = 0; e < 8; ++e) {
      float4 w = ip[e];
      Xs[(e * 4 + 0) * 260 + tid] = w.x;
      Xs[(e * 4 + 1) * 260 + tid] = w.y;
      Xs[(e * 4 + 2) * 260 + tid] = w.z;
      Xs[(e * 4 + 3) * 260 + tid] = w.w;
    }
    {
      int kw = tid >> 3, hw = (tid & 7) * 8;
      const float4* wp = (const float4*)(Wc + (size_t)(kk + kw) * HH + ht * 64 + hw);
      float4 w0 = wp[0], w1 = wp[1];
      float* d = Ws + kw * 64 + hw;
      ((float4*)d)[0] = w0; ((float4*)d)[1] = w1;
    }
    __syncthreads();
#pragma unroll 8
    for (int k = 0; k < 32; ++k) {
      float xr[4];
#pragma unroll
      for (int j = 0; j < 4; ++j) xr[j] = Xs[k * 260 + ts + 64 * j];
      const float4* wr4 = (const float4*)(Ws + k * 64 + th * 16);
#pragma unroll
      for (int i4 = 0; i4 < 4; ++i4) {
        float4 w = wr4[i4];
        float wv[4] = {w.x, w.y, w.z, w.w};
#pragma unroll
        for (int c = 0; c < 4; ++c)
#pragma unroll
          for (int j = 0; j < 4; ++j) acc[i4 * 4 + c][j] += wv[c] * xr[j];
      }
    }
    __syncthreads();
  }
#pragma unroll
  for (int i = 0; i < 16; ++i) {
    int h = ht * 64 + th * 16 + i;
    float bcv = bc[h];
    int8_t* orow = enc8 + (size_t)b * (HH * SS) + (size_t)h * SS + ts;
#pragma unroll
    for (int j = 0; j < 4; ++j) {
      float q = rintf(fminf(fmaxf((acc[i][j] + bcv) * ENC_SCALE, -127.f), 127.f));
      orow[64 * j] = (int8_t)(int)q;
    }
  }
}

// ---------------- Phase A2: G[b][j][k][q] = half( inputs[b,j,:] @ Wq[k] ) ----------------
__global__ __launch_bounds__(256) void k_G(const float* __restrict__ inputs,
                                           const float* __restrict__ Wq,
                                           __half* __restrict__ G) {
  const int qt = blockIdx.x;
  const int b  = blockIdx.y;
  const int k  = blockIdx.z;
  const int tid = threadIdx.x;
  const int ql = tid & 63, tj = tid >> 6;
  __shared__ float Xs[32 * 260];
  __shared__ float Ws[32 * 64];
  float acc[64];
#pragma unroll
  for (int j = 0; j < 64; ++j) acc[j] = 0.f;
  const int q = qt * 64 + ql;
  const float* Arow = inputs + ((size_t)b * SS + tid) * HH;
  const float* Wqk = Wq + (size_t)k * HH * QQ;
  for (int kk = 0; kk < HH; kk += 32) {
    const float4* ip = (const float4*)(Arow + kk);
#pragma unroll
    for (int e = 0; e < 8; ++e) {
      float4 w = ip[e];
      Xs[(e * 4 + 0) * 260 + tid] = w.x;
      Xs[(e * 4 + 1) * 260 + tid] = w.y;
      Xs[(e * 4 + 2) * 260 + tid] = w.z;
      Xs[(e * 4 + 3) * 260 + tid] = w.w;
    }
    {
      int hh = tid >> 3, qw = (tid & 7) * 8;
      const float* src = Wqk + (size_t)(kk + hh) * QQ;
      float* d = Ws + hh * 64 + qw;
#pragma unroll
      for (int e = 0; e < 8; ++e) {
        int qg = qt * 64 + qw + e;
        d[e] = (qg < QQ) ? src[qg] : 0.f;
      }
    }
    __syncthreads();
#pragma unroll 4
    for (int k2 = 0; k2 < 32; ++k2) {
      float wr = Ws[k2 * 64 + ql];
      const float4* xp = (const float4*)(Xs + k2 * 260 + tj * 64);
#pragma unroll
      for (int j4 = 0; j4 < 16; ++j4) {
        float4 x = xp[j4];
        acc[j4 * 4 + 0] += wr * x.x;
        acc[j4 * 4 + 1] += wr * x.y;
        acc[j4 * 4 + 2] += wr * x.z;
        acc[j4 * 4 + 3] += wr * x.w;
      }
    }
    __syncthreads();
  }
  if (q < QQ) {
#pragma unroll
    for (int j = 0; j < 64; ++j) {
      size_t jg = (size_t)b * SS + (tj * 64 + j);
      G[(jg * 3 + k) * QQ + q] = __float2half(acc[j]);
    }
  }
}

// ---------------- W2 pack: W2[qp][h] = half2(w_q[2qp][h], w_q[2qp+1][h]), qp<184 ----------------
__global__ __launch_bounds__(1024) void k_w2(const float* __restrict__ w_q,
                                             __half2* __restrict__ W2) {
  int t = blockIdx.x * 1024 + threadIdx.x;
  if (t < QP2 * HH) {
    int qp = t / HH, h = t % HH;
    float a = (2 * qp < QQ) ? w_q[(size_t)(2 * qp) * HH + h] : 0.f;
    float b = (2 * qp + 1 < QQ) ? w_q[(size_t)(2 * qp + 1) * HH + h] : 0.f;
    W2[t] = __floats2half2_rn(a, b);
  }
}

// ---------------- Main scan ----------------
// Round-11 change: P3 exp2 -> 1 KB LDS LUT. e^{2(enc+eq)} = E*F with
// E = lut[enc byte] (256 possible values) and F = exp2(CC*eq) computed once
// per h in P2's tail (evq.x now holds F, like round 3). P3 per element:
// extract + LDS LUT read + fmaf(E,F,1) + rcp + fma — drops the 8-cyc exp2
// and 2 VALU ops per element (131072 elements/step). Verified numerically in
// round 3 (same factorization, absmax 254 passed).
__global__ __launch_bounds__(1024, 4) void k_scan(
    const __half2* __restrict__ W2, const float* __restrict__ v,
    const int8_t* __restrict__ enc8, const __half* __restrict__ G,
    float* __restrict__ out, double* __restrict__ lpb, double* __restrict__ entb) {
  const int b = blockIdx.x;
  const int tid = (int)threadIdx.x;
  const int lane = tid & 63;
  const int wid = tid >> 6;            // 16 waves
  // P2 geometry: lane = q_sub*8 + hq; q_sub 0..7 (23 q-pairs each), hq 0..7 (4 h each)
  const int q_sub = lane >> 3;
  const int hq = lane & 7;
  // P3 geometry
  const int hl = lane >> 5;            // 0..1
  const int sl = lane & 31;
  const int sbase = sl * 8;
  // P4 geometry: 4 threads per s
  const int s4 = tid >> 2;             // 0..255
  const int rq = tid & 3;              // 0..3

  __shared__ uint2 enc_lds[HH * 32];   // 131072 B: enc8[b] linear, uint2[h][sl]
  __shared__ float lut[256];           // exp2(int8 * ENC_INV), indexed by raw byte
  __shared__ float2 evq[HH];           // .x = exp2(CC*eq[h]) (per step), .y = -2*v[h]
  __shared__ __half2 q2_s[QP2];        // current query as q-pairs (relu'd), pad zeroed
  __shared__ float q12_s[QP];          // prefetched G0+G1 for next step (float)
  __shared__ float part[16][260];      // +4 pad: P4 spread reads near-conflict-free
  __shared__ float m_s[SS];
  __shared__ float mask_s[SS];
  __shared__ float4 wred[16];
  __shared__ int hist[3];
  __shared__ float Vtot_s;

  // ---- init ----
  if (tid < HH) evq[tid] = make_float2(1.0f, -2.0f * v[tid]);  // F = exp2(0) = 1
  if (tid < 256) lut[tid] = EXP2F((float)(int)(int8_t)(uint8_t)tid * ENC_INV);
  if (tid < SS) mask_s[tid] = 0.f;
  if (tid < QP) q12_s[tid] = 0.f;
  if (tid < QP2) q2_s[tid] = __floats2half2_rn(0.f, 0.f);
  if (tid < 3) hist[tid] = -1;
  if (tid < 64) {
    float s = 0.f;
#pragma unroll
    for (int j = 0; j < 8; ++j) s += v[tid + 64 * j];
#pragma unroll
    for (int off = 32; off; off >>= 1) s += __shfl_xor(s, off);
    if (tid == 0) Vtot_s = s;
  }
  // ---- enc8[b] -> LDS, once (16B granules, coalesced) ----
  {
    const uint4* src = (const uint4*)(enc8 + (size_t)b * (HH * SS));
    uint4* dst = (uint4*)enc_lds;
#pragma unroll
    for (int it = 0; it < 8; ++it)
      dst[it * 1024 + tid] = src[it * 1024 + tid];
  }
  __syncthreads();
  const float Vtot = Vtot_s;

  const __half* Gb = G + (size_t)b * SS * 3 * QQ;
  const __half2* wp2 = W2 + (size_t)(q_sub * 23) * HH + (wid << 5) + (hq << 2);
  // this thread's enc rows: (wid*32 + 2i + hl), s-slot sl
  const uint2* encL = enc_lds + ((size_t)(wid * 32 + hl) * 32) + sl;

  double lp_acc = 0.0, ent_acc = 0.0;
  int first_idx = 0;

  for (int t = 0; t < SS; ++t) {
    // ---- G prefetch issue (next-step q12) ----
    const int p0 = hist[1], p1 = hist[2];
    uint2 g0raw = make_uint2(0, 0), g1raw = make_uint2(0, 0);
    const bool pf = (tid < 90);
    if (pf) {
      if (p0 >= 0) g0raw = *(const uint2*)(Gb + ((size_t)p0 * 3 + 0) * QQ + 4 * tid);
      if (p1 >= 0) g1raw = *(const uint2*)(Gb + ((size_t)p1 * 3 + 1) * QQ + 4 * tid);
    }

    // ---- P2: eq over own 32-h slice; lane covers 4 h, 23 q-pairs (fdot2) ----
    {
      float a[4];
#pragma unroll
      for (int j = 0; j < 4; ++j) a[j] = 0.f;
      const __half2* qsp = q2_s + q_sub * 23;
#pragma unroll 4
      for (int i = 0; i < 23; ++i) {
        uint4 raw = *(const uint4*)(wp2 + (size_t)i * HH);   // 4 half2 (4 h, 1 q-pair)
        __half2 qv = qsp[i];
#if __has_builtin(__builtin_amdgcn_fdot2)
        f16x2 qf = *(f16x2*)&qv;
        a[0] = __builtin_amdgcn_fdot2(qf, *(f16x2*)&raw.x, a[0], false);
        a[1] = __builtin_amdgcn_fdot2(qf, *(f16x2*)&raw.y, a[1], false);
        a[2] = __builtin_amdgcn_fdot2(qf, *(f16x2*)&raw.z, a[2], false);
        a[3] = __builtin_amdgcn_fdot2(qf, *(f16x2*)&raw.w, a[3], false);
#else
        float2 qf = __half22float2(qv);
        float2 w0 = __half22float2(*(const __half2*)&raw.x);
        float2 w1 = __half22float2(*(const __half2*)&raw.y);
        float2 w2 = __half22float2(*(const __half2*)&raw.z);
        float2 w3 = __half22float2(*(const __half2*)&raw.w);
        a[0] = fmaf(qf.x, w0.x, fmaf(qf.y, w0.y, a[0]));
        a[1] = fmaf(qf.x, w1.x, fmaf(qf.y, w1.y, a[1]));
        a[2] = fmaf(qf.x, w2.x, fmaf(qf.y, w2.y, a[2]));
        a[3] = fmaf(qf.x, w3.x, fmaf(qf.y, w3.y, a[3]));
#endif
      }
#pragma unroll
      for (int off = 8; off <= 32; off <<= 1)
#pragma unroll
        for (int j = 0; j < 4; ++j) a[j] += __shfl_xor(a[j], off);
      if (lane < 8) {        // q_sub==0, hq==lane
        int h0 = (wid << 5) + (lane << 2);
        evq[h0 + 0].x = EXP2F(CC * a[0]);
        evq[h0 + 1].x = EXP2F(CC * a[1]);
        evq[h0 + 2].x = EXP2F(CC * a[2]);
        evq[h0 + 3].x = EXP2F(CC * a[3]);
      }
      // no barrier: each wave reads only its own evq slice (in-wave ordering)
    }

    // ---- P3: scores; enc bytes from LDS, E via 1 KB LUT ----
    {
      float acc[8];
#pragma unroll
      for (int j = 0; j < 8; ++j) acc[j] = 0.f;
#pragma unroll
      for (int i = 0; i < 16; ++i) {
        float2 ev = evq[(wid << 5) + 2 * i + hl];
        const float F = ev.x, mv = ev.y;
        uint2 w = encL[(size_t)(2 * i) * 32];
        const uint32_t w0 = w.x, w1 = w.y;
#pragma unroll
        for (int k = 0; k < 4; ++k) {
          {
            float E = lut[(w0 >> (8 * k)) & 0xFF];
            float d = fmaf(E, F, 1.0f);
            acc[k] = fmaf(mv, frcp(d), acc[k]);
          }
          {
            float E = lut[(w1 >> (8 * k)) & 0xFF];
            float d = fmaf(E, F, 1.0f);
            acc[4 + k] = fmaf(mv, frcp(d), acc[4 + k]);
          }
        }
      }
#pragma unroll
      for (int j = 0; j < 8; ++j) acc[j] += __shfl_xor(acc[j], 32);
      if (hl == 0) {
        *(float4*)&part[wid][sbase]     = make_float4(acc[0], acc[1], acc[2], acc[3]);
        *(float4*)&part[wid][sbase + 4] = make_float4(acc[4], acc[5], acc[6], acc[7]);
      }
    }

    // ---- consume q12 prefetch ----
    if (pf) {
      float2 f0a = __half22float2(*(const __half2*)&g0raw.x);
      float2 f0b = __half22float2(*(const __half2*)&g0raw.y);
      float2 f1a = __half22float2(*(const __half2*)&g1raw.x);
      float2 f1b = __half22float2(*(const __half2*)&g1raw.y);
      float4 qv;
      qv.x = f0a.x + f1a.x; qv.y = f0a.y + f1a.y;
      qv.z = f0b.x + f1b.x; qv.w = f0b.y + f1b.y;
      *(float4*)&q12_s[4 * tid] = qv;
    }

    // ---- gumbel + mask for P4 (2 regs live across b1 only) ----
    float gum, maskv;
    {
      TF2 o = threefry(c_keys.sk[t][0], c_keys.sk[t][1], 0u, (uint32_t)(b * SS + s4));
      float fb = __uint_as_float((o.b >> 9) | 0x3f800000u) - 1.0f;
      fb = fmaxf(fb, 1.0e-12f);
      gum = -__logf(-__logf(fb));
      maskv = mask_s[s4];
    }
    __syncthreads();   // b1: part, q12 ready

    // ================== P4: all 16 waves, 4 threads per s ==================
    {
      float a = part[rq * 4 + 0][s4];
      a += part[rq * 4 + 1][s4];
      a += part[rq * 4 + 2][s4];
      a += part[rq * 4 + 3][s4];
      a += __shfl_xor(a, 1);
      a += __shfl_xor(a, 2);          // all 4 rq lanes: full 16-row sum
      float sc = Vtot + a;
      float logit = 10.0f * fast_tanh(sc);
      float m = (maskv != 0.f) ? -1.0e8f : logit;
      if (rq == 0) m_s[s4] = m;
      float z = m + gum;
      float e = __expf(m);            // masked -> exactly 0
      float em = e * m;
      int si = s4;
#pragma unroll
      for (int off = 4; off <= 32; off <<= 1) {
        float zo = __shfl_xor(z, off);
        int io = __shfl_xor(si, off);
        if (zo > z || (zo == z && io < si)) { z = zo; si = io; }
        e += __shfl_xor(e, off);
        em += __shfl_xor(em, off);
      }
      if (lane == 0) wred[wid] = make_float4(z, __int_as_float(si), e, em);
    }
    __syncthreads();   // b2: wred, m_s ready

    // ================== finalize (all threads) + next-q build ==================
    {
      float4 r0 = wred[0];
      float z = r0.x; int si = __float_as_int(r0.y);
      float se = r0.z, sem = r0.w;
#pragma unroll
      for (int r = 1; r < 16; ++r) {
        float4 rv = wred[r];
        int io = __float_as_int(rv.y);
        if (rv.x > z || (rv.x == z && io < si)) { z = rv.x; si = io; }
        se += rv.z; sem += rv.w;
      }
      const int idx = si;
      if (pf) {   // tid < 90: q = relu(q12 + G2[idx]) -> q2_s half2 pairs
        uint2 g2 = *(const uint2*)(Gb + ((size_t)idx * 3 + 2) * QQ + 4 * tid);
        float2 f2a = __half22float2(*(const __half2*)&g2.x);
        float2 f2b = __half22float2(*(const __half2*)&g2.y);
        float4 q12v = *(const float4*)&q12_s[4 * tid];
        float4 qn;
        qn.x = fmaxf(q12v.x + f2a.x, 0.f);
        qn.y = fmaxf(q12v.y + f2a.y, 0.f);
        qn.z = fmaxf(q12v.z + f2b.x, 0.f);
        qn.w = fmaxf(q12v.w + f2b.y, 0.f);
        q2_s[2 * tid]     = __floats2half2_rn(qn.x, qn.y);
        q2_s[2 * tid + 1] = __floats2half2_rn(qn.z, qn.w);
      }
      if (tid == 0) {
        float lse = __logf(se);
        float mi = m_s[idx];
        lp_acc += (double)(mi - lse);
        ent_acc += (double)(lse - sem / se);
        out[b * 257 + t] = (float)idx;
        mask_s[idx] = 1.0f;
        hist[0] = hist[1]; hist[1] = hist[2]; hist[2] = idx;
        if (t == 0) first_idx = idx;
      }
    }
    __syncthreads();   // b3: q2_s, hist, mask updated
  }

  if (tid == 0) {
    out[b * 257 + 256] = (float)first_idx;
    lpb[b] = lp_acc;
    entb[b] = ent_acc;
  }
}

// ---------------- Final deterministic reduction ----------------
__global__ void k_final(const double* __restrict__ lpb,
                        const double* __restrict__ entb, float* __restrict__ out) {
  if (threadIdx.x == 0) {
    double a = 0.0, c = 0.0;
    for (int i = 0; i < BB; ++i) { a += lpb[i]; c += entb[i]; }
    out[BB * 257 + 0] = (float)a;
    out[BB * 257 + 1] = (float)c;
  }
}

extern "C" void kernel_launch(void* const* d_in, const int* in_sizes, int n_in,
                              void* d_out, int out_size, void* d_ws, size_t ws_size,
                              hipStream_t stream) {
  const float* inputs = (const float*)d_in[0];
  const float* Wc  = (const float*)d_in[1];
  const float* bc  = (const float*)d_in[2];
  const float* Wq  = (const float*)d_in[3];
  const float* w_q = (const float*)d_in[4];
  const float* v   = (const float*)d_in[5];
  float* out = (float*)d_out;

  char* ws = (char*)d_ws;
  const size_t encBytes = (size_t)BB * HH * SS;            // 16.8 MB int8
  const size_t gBytes   = (size_t)3 * BB * SS * QQ * 2;    // 70.8 MB fp16
  const size_t w2Bytes  = (size_t)QP2 * HH * 4;            // 377 KB half2 (q-pair packed)
  int8_t* enc8 = (int8_t*)ws;
  __half* G   = (__half*)(ws + encBytes);
  __half2* W2 = (__half2*)(ws + encBytes + gBytes);
  size_t goff = (encBytes + gBytes + w2Bytes + 1023) & ~(size_t)1023;
  double* lpb = (double*)(ws + goff);
  double* entb = lpb + BB;

  dim3 gA1(8, BB);
  k_enc<<<gA1, 256, 0, stream>>>(inputs, Wc, bc, enc8);
  dim3 gA2(6, BB, 3);
  k_G<<<gA2, 256, 0, stream>>>(inputs, Wq, G);
  k_w2<<<(QP2 * HH + 1023) / 1024, 1024, 0, stream>>>(w_q, W2);
  k_scan<<<BB, 1024, 0, stream>>>(W2, v, enc8, G, out, lpb, entb);
  k_final<<<1, 64, 0, stream>>>(lpb, entb, out);
}

// Round 12
// 3850.955 us; speedup vs baseline: 4.4380x; 1.2210x over previous
//
#include <hip/hip_runtime.h>
#include <hip/hip_fp16.h>
#include <stdint.h>

#define BB 128
#define SS 256
#define HH 512
#define QQ 360
#define QP 384    // padded q (32 subsets... 192 q-pairs), pad zeroed
#define QP2 192   // q-pairs (16 subsets x 12)
#define HF 256    // h per block (half of HH)

// ---------------- Threefry-2x32 (JAX semantics) ----------------
struct TF2 { uint32_t a, b; };

__host__ __device__ constexpr uint32_t rotl32(uint32_t x, int d) {
  return (x << d) | (x >> (32 - d));
}

__host__ __device__ constexpr TF2 threefry(uint32_t k0, uint32_t k1,
                                           uint32_t x0, uint32_t x1) {
  uint32_t ks[3] = {k0, k1, k0 ^ k1 ^ 0x1BD11BDAu};
  x0 += ks[0]; x1 += ks[1];
  const int R0[4] = {13, 15, 26, 6};
  const int R1[4] = {17, 29, 16, 24};
  for (int g = 0; g < 5; ++g) {
    const int* r = (g & 1) ? R1 : R0;
    for (int i = 0; i < 4; ++i) { x0 += x1; x1 = rotl32(x1, r[i]); x1 ^= x0; }
    x0 += ks[(g + 1) % 3];
    x1 += ks[(g + 2) % 3] + (uint32_t)(g + 1);
  }
  return TF2{x0, x1};
}

struct KeyTab { uint32_t sk[256][2]; };
constexpr KeyTab make_keys() {
  KeyTab K{};
  uint32_t k0 = 0u, k1 = 1u;
  for (int t = 0; t < 256; ++t) {
    TF2 nk = threefry(k0, k1, 0u, 0u);
    TF2 sk = threefry(k0, k1, 0u, 1u);
    K.sk[t][0] = sk.a; K.sk[t][1] = sk.b;
    k0 = nk.a; k1 = nk.b;
  }
  return K;
}
__constant__ KeyTab c_keys = make_keys();

// ---------------- fast math helpers ----------------
__device__ __forceinline__ float frcp(float x) {
#if __has_builtin(__builtin_amdgcn_rcpf)
  return __builtin_amdgcn_rcpf(x);
#else
  return 1.0f / x;
#endif
}

#if __has_builtin(__builtin_amdgcn_exp2f)
  #define EXP2F(x) __builtin_amdgcn_exp2f(x)
  #define CC 2.8853900817779268f
#else
  #define EXP2F(x) __expf(x)
  #define CC 2.0f
#endif

#define ENC_SCALE 21.0f
#define ENC_INV (CC / ENC_SCALE)

__device__ __forceinline__ float fast_tanh(float x) {
  float e = __expf(2.0f * x);
  return 1.0f - 2.0f * frcp(e + 1.0f);
}

typedef _Float16 f16x2 __attribute__((ext_vector_type(2)));

// ---------------- Phase A1: enc8[b][h][s] = int8( 21 * (inputs @ Wc + bc)^T ) ----------------
__global__ __launch_bounds__(256) void k_enc(const float* __restrict__ inputs,
                                             const float* __restrict__ Wc,
                                             const float* __restrict__ bc,
                                             int8_t* __restrict__ enc8) {
  const int ht = blockIdx.x;
  const int b  = blockIdx.y;
  const int tid = threadIdx.x;
  const int ts = tid & 63, th = tid >> 6;
  __shared__ float Xs[32 * 260];
  __shared__ float Ws[32 * 64];
  float acc[16][4];
#pragma unroll
  for (int i = 0; i < 16; ++i)
#pragma unroll
    for (int j = 0; j < 4; ++j) acc[i][j] = 0.f;

  const float* Arow = inputs + ((size_t)b * SS + tid) * HH;
  for (int kk = 0; kk < HH; kk += 32) {
    const float4* ip = (const float4*)(Arow + kk);
#pragma unroll
    for (int e = 0; e < 8; ++e) {
      float4 w = ip[e];
      Xs[(e * 4 + 0) * 260 + tid] = w.x;
      Xs[(e * 4 + 1) * 260 + tid] = w.y;
      Xs[(e * 4 + 2) * 260 + tid] = w.z;
      Xs[(e * 4 + 3) * 260 + tid] = w.w;
    }
    {
      int kw = tid >> 3, hw = (tid & 7) * 8;
      const float4* wp = (const float4*)(Wc + (size_t)(kk + kw) * HH + ht * 64 + hw);
      float4 w0 = wp[0], w1 = wp[1];
      float* d = Ws + kw * 64 + hw;
      ((float4*)d)[0] = w0; ((float4*)d)[1] = w1;
    }
    __syncthreads();
#pragma unroll 8
    for (int k = 0; k < 32; ++k) {
      float xr[4];
#pragma unroll
      for (int j = 0; j < 4; ++j) xr[j] = Xs[k * 260 + ts + 64 * j];
      const float4* wr4 = (const float4*)(Ws + k * 64 + th * 16);
#pragma unroll
      for (int i4 = 0; i4 < 4; ++i4) {
        float4 w = wr4[i4];
        float wv[4] = {w.x, w.y, w.z, w.w};
#pragma unroll
        for (int c = 0; c < 4; ++c)
#pragma unroll
          for (int j = 0; j < 4; ++j) acc[i4 * 4 + c][j] += wv[c] * xr[j];
      }
    }
    __syncthreads();
  }
#pragma unroll
  for (int i = 0; i < 16; ++i) {
    int h = ht * 64 + th * 16 + i;
    float bcv = bc[h];
    int8_t* orow = enc8 + (size_t)b * (HH * SS) + (size_t)h * SS + ts;
#pragma unroll
    for (int j = 0; j < 4; ++j) {
      float q = rintf(fminf(fmaxf((acc[i][j] + bcv) * ENC_SCALE, -127.f), 127.f));
      orow[64 * j] = (int8_t)(int)q;
    }
  }
}

// ---------------- Phase A2: G[b][j][k][q] = half( inputs[b,j,:] @ Wq[k] ) ----------------
__global__ __launch_bounds__(256) void k_G(const float* __restrict__ inputs,
                                           const float* __restrict__ Wq,
                                           __half* __restrict__ G) {
  const int qt = blockIdx.x;
  const int b  = blockIdx.y;
  const int k  = blockIdx.z;
  const int tid = threadIdx.x;
  const int ql = tid & 63, tj = tid >> 6;
  __shared__ float Xs[32 * 260];
  __shared__ float Ws[32 * 64];
  float acc[64];
#pragma unroll
  for (int j = 0; j < 64; ++j) acc[j] = 0.f;
  const int q = qt * 64 + ql;
  const float* Arow = inputs + ((size_t)b * SS + tid) * HH;
  const float* Wqk = Wq + (size_t)k * HH * QQ;
  for (int kk = 0; kk < HH; kk += 32) {
    const float4* ip = (const float4*)(Arow + kk);
#pragma unroll
    for (int e = 0; e < 8; ++e) {
      float4 w = ip[e];
      Xs[(e * 4 + 0) * 260 + tid] = w.x;
      Xs[(e * 4 + 1) * 260 + tid] = w.y;
      Xs[(e * 4 + 2) * 260 + tid] = w.z;
      Xs[(e * 4 + 3) * 260 + tid] = w.w;
    }
    {
      int hh = tid >> 3, qw = (tid & 7) * 8;
      const float* src = Wqk + (size_t)(kk + hh) * QQ;
      float* d = Ws + hh * 64 + qw;
#pragma unroll
      for (int e = 0; e < 8; ++e) {
        int qg = qt * 64 + qw + e;
        d[e] = (qg < QQ) ? src[qg] : 0.f;
      }
    }
    __syncthreads();
#pragma unroll 4
    for (int k2 = 0; k2 < 32; ++k2) {
      float wr = Ws[k2 * 64 + ql];
      const float4* xp = (const float4*)(Xs + k2 * 260 + tj * 64);
#pragma unroll
      for (int j4 = 0; j4 < 16; ++j4) {
        float4 x = xp[j4];
        acc[j4 * 4 + 0] += wr * x.x;
        acc[j4 * 4 + 1] += wr * x.y;
        acc[j4 * 4 + 2] += wr * x.z;
        acc[j4 * 4 + 3] += wr * x.w;
      }
    }
    __syncthreads();
  }
  if (q < QQ) {
#pragma unroll
    for (int j = 0; j < 64; ++j) {
      size_t jg = (size_t)b * SS + (tj * 64 + j);
      G[(jg * 3 + k) * QQ + q] = __float2half(acc[j]);
    }
  }
}

// ---------------- W2 pack: W2[qp][h] = half2(w_q[2qp][h], w_q[2qp+1][h]), qp<192 ----------------
__global__ __launch_bounds__(1024) void k_w2(const float* __restrict__ w_q,
                                             __half2* __restrict__ W2) {
  int t = blockIdx.x * 1024 + threadIdx.x;
  if (t < QP2 * HH) {
    int qp = t / HH, h = t % HH;
    float a = (2 * qp < QQ) ? w_q[(size_t)(2 * qp) * HH + h] : 0.f;
    float b = (2 * qp + 1 < QQ) ? w_q[(size_t)(2 * qp + 1) * HH + h] : 0.f;
    W2[t] = __floats2half2_rn(a, b);
  }
}

// ---------------- Main scan: 2 blocks per batch (h-split), pairwise exchange ----------------
// Block bid: batch b = bid&127, half = bid>>7 owns h in [half*256, half*256+256).
// Per step: each block computes own_sum[s] over its 256 h, publishes via
// agent-scope atomics (double-buffered by t&1), release-flag + relaxed-poll,
// then BOTH blocks redundantly run sampling (sA+sB commutative => bitwise
// identical; threefry deterministic) so mask/hist/q stay in lockstep with NO
// second exchange. Only half 0 writes outputs.
__global__ __launch_bounds__(1024, 4) void k_scan(
    const __half2* __restrict__ W2, const float* __restrict__ v,
    const int8_t* __restrict__ enc8, const __half* __restrict__ G,
    float* __restrict__ xm, uint32_t* __restrict__ xflag,
    float* __restrict__ out, double* __restrict__ lpb, double* __restrict__ entb) {
  const int bid = blockIdx.x;
  const int b = bid & 127;
  const int half = bid >> 7;
  const int tid = (int)threadIdx.x;
  const int lane = tid & 63;
  const int wid = tid >> 6;            // 16 waves
  // P2 geometry: lane = q_sub*4 + hq2; q_sub 0..15 (12 q-pairs each), hq2 0..3 (4 h each)
  const int q_sub = lane >> 2;
  const int hq2 = lane & 3;
  // P3 geometry: wave owns 16 local h; lane-half owns 8 of them
  const int hl = lane >> 5;            // 0..1
  const int sl = lane & 31;
  const int sbase = sl * 8;
  // P4 geometry: 4 threads per s
  const int s4 = tid >> 2;             // 0..255
  const int rq = tid & 3;              // 0..3

  __shared__ uint2 enc_lds[HF * 32];   // 64 KB: own h-slice, uint2[h_loc][sl]
  __shared__ float2 evq[HF];           // .x = CC*eq[h] (per step), .y = -2*v[h]
  __shared__ __half2 q2_s[QP2];        // current query q-pairs (relu'd), pad zeroed
  __shared__ float q12_s[QP];          // prefetched G0+G1 for next step
  __shared__ float part[16][260];
  __shared__ float m_s[SS];
  __shared__ float mask_s[SS];
  __shared__ float4 wred[16];
  __shared__ int hist[3];
  __shared__ float Vtot_s;

  const int hbase = half * HF;

  // ---- init ----
  if (tid < HF) evq[tid] = make_float2(0.f, -2.0f * v[hbase + tid]);
  if (tid < SS) mask_s[tid] = 0.f;
  if (tid < QP) q12_s[tid] = 0.f;
  if (tid < QP2) q2_s[tid] = __floats2half2_rn(0.f, 0.f);
  if (tid < 3) hist[tid] = -1;
  if (tid < 64) {
    float s = 0.f;
#pragma unroll
    for (int j = 0; j < 8; ++j) s += v[tid + 64 * j];   // FULL 512-h sum
#pragma unroll
    for (int off = 32; off; off >>= 1) s += __shfl_xor(s, off);
    if (tid == 0) Vtot_s = s;
  }
  // ---- own enc half -> LDS (64 KB, coalesced) ----
  {
    const uint4* src4 = (const uint4*)(enc8 + (size_t)b * (HH * SS) + (size_t)hbase * SS);
    uint4* dst4 = (uint4*)enc_lds;
#pragma unroll
    for (int it = 0; it < 4; ++it)
      dst4[it * 1024 + tid] = src4[it * 1024 + tid];
  }
  __syncthreads();
  const float Vtot = Vtot_s;

  const __half* Gb = G + (size_t)b * SS * 3 * QQ;
  const __half2* wp2 = W2 + (size_t)(q_sub * 12) * HH + hbase + wid * 16 + hq2 * 4;
  const uint2* encL = enc_lds + (size_t)(wid * 16 + hl) * 32 + sl;
  float* xm_my = xm + (size_t)(b * 2 + half) * 512;
  const float* xm_pr = xm + (size_t)(b * 2 + (1 - half)) * 512;
  uint32_t* flag_my = xflag + (size_t)bid * 16;
  uint32_t* flag_pr = xflag + (size_t)(bid ^ 128) * 16;

  double lp_acc = 0.0, ent_acc = 0.0;
  int first_idx = 0;

  for (int t = 0; t < SS; ++t) {
    // ---- G prefetch issue (next-step q12) ----
    const int p0 = hist[1], p1 = hist[2];
    uint2 g0raw = make_uint2(0, 0), g1raw = make_uint2(0, 0);
    const bool pf = (tid < 90);
    if (pf) {
      if (p0 >= 0) g0raw = *(const uint2*)(Gb + ((size_t)p0 * 3 + 0) * QQ + 4 * tid);
      if (p1 >= 0) g1raw = *(const uint2*)(Gb + ((size_t)p1 * 3 + 1) * QQ + 4 * tid);
    }

    // ---- gumbel + mask (deterministic; identical in both halves) ----
    float gum, maskv;
    {
      TF2 o = threefry(c_keys.sk[t][0], c_keys.sk[t][1], 0u, (uint32_t)(b * SS + s4));
      float fb = __uint_as_float((o.b >> 9) | 0x3f800000u) - 1.0f;
      fb = fmaxf(fb, 1.0e-12f);
      gum = -__logf(-__logf(fb));
      maskv = mask_s[s4];
    }

    // ---- P2: eq over own 16-h wave slice; lane: 4 h x 12 q-pairs (fdot2) ----
    {
      float a[4];
#pragma unroll
      for (int j = 0; j < 4; ++j) a[j] = 0.f;
      const __half2* qsp = q2_s + q_sub * 12;
#pragma unroll 4
      for (int i = 0; i < 12; ++i) {
        uint4 raw = *(const uint4*)(wp2 + (size_t)i * HH);   // 4 half2 (4 h, 1 q-pair)
        __half2 qv = qsp[i];
#if __has_builtin(__builtin_amdgcn_fdot2)
        f16x2 qf = *(f16x2*)&qv;
        a[0] = __builtin_amdgcn_fdot2(qf, *(f16x2*)&raw.x, a[0], false);
        a[1] = __builtin_amdgcn_fdot2(qf, *(f16x2*)&raw.y, a[1], false);
        a[2] = __builtin_amdgcn_fdot2(qf, *(f16x2*)&raw.z, a[2], false);
        a[3] = __builtin_amdgcn_fdot2(qf, *(f16x2*)&raw.w, a[3], false);
#else
        float2 qf = __half22float2(qv);
        float2 w0 = __half22float2(*(const __half2*)&raw.x);
        float2 w1 = __half22float2(*(const __half2*)&raw.y);
        float2 w2 = __half22float2(*(const __half2*)&raw.z);
        float2 w3 = __half22float2(*(const __half2*)&raw.w);
        a[0] = fmaf(qf.x, w0.x, fmaf(qf.y, w0.y, a[0]));
        a[1] = fmaf(qf.x, w1.x, fmaf(qf.y, w1.y, a[1]));
        a[2] = fmaf(qf.x, w2.x, fmaf(qf.y, w2.y, a[2]));
        a[3] = fmaf(qf.x, w3.x, fmaf(qf.y, w3.y, a[3]));
#endif
      }
#pragma unroll
      for (int off = 4; off <= 32; off <<= 1)
#pragma unroll
        for (int j = 0; j < 4; ++j) a[j] += __shfl_xor(a[j], off);
      if (lane < 4) {        // q_sub==0, hq2==lane
        int h0 = wid * 16 + lane * 4;
#pragma unroll
        for (int j = 0; j < 4; ++j) evq[h0 + j].x = CC * a[j];
      }
      // no barrier: P3 wave reads only its own wave's evq slice
    }

    // ---- P3: own-half scores (8 h per lane-half, exp2 form) ----
    {
      float acc[8];
#pragma unroll
      for (int j = 0; j < 8; ++j) acc[j] = 0.f;
#pragma unroll
      for (int i = 0; i < 8; ++i) {
        float2 ev = evq[wid * 16 + 2 * i + hl];
        const float eqC = ev.x, mv = ev.y;
        uint2 w = encL[(size_t)(2 * i) * 32];
        const uint32_t w0 = w.x, w1 = w.y;
#pragma unroll
        for (int k = 0; k < 4; ++k) {
          {
            float f = (float)(int)(int8_t)(w0 >> (8 * k));
            float e = EXP2F(fmaf(f, ENC_INV, eqC));
            acc[k] = fmaf(mv, frcp(e + 1.0f), acc[k]);
          }
          {
            float f = (float)(int)(int8_t)(w1 >> (8 * k));
            float e = EXP2F(fmaf(f, ENC_INV, eqC));
            acc[4 + k] = fmaf(mv, frcp(e + 1.0f), acc[4 + k]);
          }
        }
      }
#pragma unroll
      for (int j = 0; j < 8; ++j) acc[j] += __shfl_xor(acc[j], 32);
      if (hl == 0) {
        *(float4*)&part[wid][sbase]     = make_float4(acc[0], acc[1], acc[2], acc[3]);
        *(float4*)&part[wid][sbase + 4] = make_float4(acc[4], acc[5], acc[6], acc[7]);
      }
    }

    // ---- consume q12 prefetch ----
    if (pf) {
      float2 f0a = __half22float2(*(const __half2*)&g0raw.x);
      float2 f0b = __half22float2(*(const __half2*)&g0raw.y);
      float2 f1a = __half22float2(*(const __half2*)&g1raw.x);
      float2 f1b = __half22float2(*(const __half2*)&g1raw.y);
      float4 qv;
      qv.x = f0a.x + f1a.x; qv.y = f0a.y + f1a.y;
      qv.z = f0b.x + f1b.x; qv.w = f0b.y + f1b.y;
      *(float4*)&q12_s[4 * tid] = qv;
    }
    __syncthreads();   // b1: part, q12 ready

    // ---- local reduce (own half-sum per s) + publish ----
    float own;
    {
      own  = part[rq * 4 + 0][s4];
      own += part[rq * 4 + 1][s4];
      own += part[rq * 4 + 2][s4];
      own += part[rq * 4 + 3][s4];
      own += __shfl_xor(own, 1);
      own += __shfl_xor(own, 2);       // all 4 rq lanes: full 16-row sum
      if (rq == 0)
        __hip_atomic_store(&xm_my[(t & 1) * 256 + s4], own,
                           __ATOMIC_RELAXED, __HIP_MEMORY_SCOPE_AGENT);
    }
    __syncthreads();   // b2: all publish stores drained (vmcnt)
    if (tid == 0) {
      __hip_atomic_store(flag_my, (uint32_t)(t + 1),
                         __ATOMIC_RELEASE, __HIP_MEMORY_SCOPE_AGENT);
      while (__hip_atomic_load(flag_pr, __ATOMIC_RELAXED,
                               __HIP_MEMORY_SCOPE_AGENT) < (uint32_t)(t + 1))
        __builtin_amdgcn_s_sleep(1);
    }
    __syncthreads();   // b2': peer data ready

    // ================== sampling (redundant in both halves) ==================
    {
      float peer = __hip_atomic_load(&xm_pr[(t & 1) * 256 + s4],
                                     __ATOMIC_RELAXED, __HIP_MEMORY_SCOPE_AGENT);
      float sc = Vtot + (own + peer);   // commutative: bitwise-identical both halves
      float logit = 10.0f * fast_tanh(sc);
      float m = (maskv != 0.f) ? -1.0e8f : logit;
      if (rq == 0) m_s[s4] = m;
      float z = m + gum;
      float e = __expf(m);              // masked -> exactly 0
      float em = e * m;
      int si = s4;
#pragma unroll
      for (int off = 4; off <= 32; off <<= 1) {
        float zo = __shfl_xor(z, off);
        int io = __shfl_xor(si, off);
        if (zo > z || (zo == z && io < si)) { z = zo; si = io; }
        e += __shfl_xor(e, off);
        em += __shfl_xor(em, off);
      }
      if (lane == 0) wred[wid] = make_float4(z, __int_as_float(si), e, em);
    }
    __syncthreads();   // b3: wred, m_s ready

    // ================== finalize (all threads) + next-q build ==================
    {
      float4 r0 = wred[0];
      float z = r0.x; int si = __float_as_int(r0.y);
      float se = r0.z, sem = r0.w;
#pragma unroll
      for (int r = 1; r < 16; ++r) {
        float4 rv = wred[r];
        int io = __float_as_int(rv.y);
        if (rv.x > z || (rv.x == z && io < si)) { z = rv.x; si = io; }
        se += rv.z; sem += rv.w;
      }
      const int idx = si;
      if (pf) {   // tid < 90: q = relu(q12 + G2[idx]) -> q2_s half2 pairs
        uint2 g2 = *(const uint2*)(Gb + ((size_t)idx * 3 + 2) * QQ + 4 * tid);
        float2 f2a = __half22float2(*(const __half2*)&g2.x);
        float2 f2b = __half22float2(*(const __half2*)&g2.y);
        float4 q12v = *(const float4*)&q12_s[4 * tid];
        float4 qn;
        qn.x = fmaxf(q12v.x + f2a.x, 0.f);
        qn.y = fmaxf(q12v.y + f2a.y, 0.f);
        qn.z = fmaxf(q12v.z + f2b.x, 0.f);
        qn.w = fmaxf(q12v.w + f2b.y, 0.f);
        q2_s[2 * tid]     = __floats2half2_rn(qn.x, qn.y);
        q2_s[2 * tid + 1] = __floats2half2_rn(qn.z, qn.w);
      }
      if (tid == 0) {
        float lse = __logf(se);
        float mi = m_s[idx];
        lp_acc += (double)(mi - lse);
        ent_acc += (double)(lse - sem / se);
        if (half == 0) out[b * 257 + t] = (float)idx;
        mask_s[idx] = 1.0f;
        hist[0] = hist[1]; hist[1] = hist[2]; hist[2] = idx;
        if (t == 0) first_idx = idx;
      }
    }
    __syncthreads();   // b4: q2_s, hist, mask updated
  }

  if (tid == 0 && half == 0) {
    out[b * 257 + 256] = (float)first_idx;
    lpb[b] = lp_acc;
    entb[b] = ent_acc;
  }
}

// ---------------- Final deterministic reduction ----------------
__global__ void k_final(const double* __restrict__ lpb,
                        const double* __restrict__ entb, float* __restrict__ out) {
  if (threadIdx.x == 0) {
    double a = 0.0, c = 0.0;
    for (int i = 0; i < BB; ++i) { a += lpb[i]; c += entb[i]; }
    out[BB * 257 + 0] = (float)a;
    out[BB * 257 + 1] = (float)c;
  }
}

extern "C" void kernel_launch(void* const* d_in, const int* in_sizes, int n_in,
                              void* d_out, int out_size, void* d_ws, size_t ws_size,
                              hipStream_t stream) {
  const float* inputs = (const float*)d_in[0];
  const float* Wc  = (const float*)d_in[1];
  const float* bc  = (const float*)d_in[2];
  const float* Wq  = (const float*)d_in[3];
  const float* w_q = (const float*)d_in[4];
  const float* v   = (const float*)d_in[5];
  float* out = (float*)d_out;

  char* ws = (char*)d_ws;
  const size_t encBytes = (size_t)BB * HH * SS;            // 16.8 MB int8
  const size_t gBytes   = (size_t)3 * BB * SS * QQ * 2;    // 70.8 MB fp16
  const size_t w2Bytes  = (size_t)QP2 * HH * 4;            // 384 KB half2
  int8_t* enc8 = (int8_t*)ws;
  __half* G   = (__half*)(ws + encBytes);
  __half2* W2 = (__half2*)(ws + encBytes + gBytes);
  size_t xoff = (encBytes + gBytes + w2Bytes + 1023) & ~(size_t)1023;
  float* xm = (float*)(ws + xoff);                          // 256 slots * 2 bufs * 256 f = 512 KB
  uint32_t* xflag = (uint32_t*)(ws + xoff + 512 * 1024);    // 256 * 16 uints = 16 KB
  double* lpb = (double*)(ws + xoff + 512 * 1024 + 16384);
  double* entb = lpb + BB;

  dim3 gA1(8, BB);
  k_enc<<<gA1, 256, 0, stream>>>(inputs, Wc, bc, enc8);
  dim3 gA2(6, BB, 3);
  k_G<<<gA2, 256, 0, stream>>>(inputs, Wq, G);
  k_w2<<<(QP2 * HH + 1023) / 1024, 1024, 0, stream>>>(w_q, W2);
  hipMemsetAsync(xflag, 0, 16384, stream);

  void* args[] = {(void*)&W2, (void*)&v, (void*)&enc8, (void*)&G,
                  (void*)&xm, (void*)&xflag, (void*)&out, (void*)&lpb, (void*)&entb};
  hipError_t ce = hipLaunchCooperativeKernel((const void*)k_scan, dim3(256), dim3(1024),
                                             args, 0, stream);
  if (ce != hipSuccess) {
    // 256 blocks x 1024 thr x ~89 KB LDS = exactly 1 block/CU on 256 CUs:
    // all blocks co-resident under a regular launch as well.
    k_scan<<<256, 1024, 0, stream>>>(W2, v, enc8, G, xm, xflag, out, lpb, entb);
  }
  k_final<<<1, 64, 0, stream>>>(lpb, entb, out);
}

// Round 13
// 3634.637 us; speedup vs baseline: 4.7021x; 1.0595x over previous
//
#include <hip/hip_runtime.h>
#include <hip/hip_fp16.h>
#include <stdint.h>

#define BB 128
#define SS 256
#define HH 512
#define QQ 360
#define QP 384    // padded q, pad zeroed
#define QP2 192   // q-pairs (16 subsets x 12)
#define HF 256    // h per block (half of HH)

// ---------------- Threefry-2x32 (JAX semantics) ----------------
struct TF2 { uint32_t a, b; };

__host__ __device__ constexpr uint32_t rotl32(uint32_t x, int d) {
  return (x << d) | (x >> (32 - d));
}

__host__ __device__ constexpr TF2 threefry(uint32_t k0, uint32_t k1,
                                           uint32_t x0, uint32_t x1) {
  uint32_t ks[3] = {k0, k1, k0 ^ k1 ^ 0x1BD11BDAu};
  x0 += ks[0]; x1 += ks[1];
  const int R0[4] = {13, 15, 26, 6};
  const int R1[4] = {17, 29, 16, 24};
  for (int g = 0; g < 5; ++g) {
    const int* r = (g & 1) ? R1 : R0;
    for (int i = 0; i < 4; ++i) { x0 += x1; x1 = rotl32(x1, r[i]); x1 ^= x0; }
    x0 += ks[(g + 1) % 3];
    x1 += ks[(g + 2) % 3] + (uint32_t)(g + 1);
  }
  return TF2{x0, x1};
}

struct KeyTab { uint32_t sk[256][2]; };
constexpr KeyTab make_keys() {
  KeyTab K{};
  uint32_t k0 = 0u, k1 = 1u;
  for (int t = 0; t < 256; ++t) {
    TF2 nk = threefry(k0, k1, 0u, 0u);
    TF2 sk = threefry(k0, k1, 0u, 1u);
    K.sk[t][0] = sk.a; K.sk[t][1] = sk.b;
    k0 = nk.a; k1 = nk.b;
  }
  return K;
}
__constant__ KeyTab c_keys = make_keys();

// ---------------- fast math helpers ----------------
__device__ __forceinline__ float frcp(float x) {
#if __has_builtin(__builtin_amdgcn_rcpf)
  return __builtin_amdgcn_rcpf(x);
#else
  return 1.0f / x;
#endif
}

#if __has_builtin(__builtin_amdgcn_exp2f)
  #define EXP2F(x) __builtin_amdgcn_exp2f(x)
  #define CC 2.8853900817779268f
#else
  #define EXP2F(x) __expf(x)
  #define CC 2.0f
#endif

#define ENC_SCALE 21.0f
#define ENC_INV (CC / ENC_SCALE)

__device__ __forceinline__ float fast_tanh(float x) {
  float e = __expf(2.0f * x);
  return 1.0f - 2.0f * frcp(e + 1.0f);
}

typedef _Float16 f16x2 __attribute__((ext_vector_type(2)));

// ---------------- Phase A1: enc8[b][h][s] = int8( 21 * (inputs @ Wc + bc)^T ) ----------------
__global__ __launch_bounds__(256) void k_enc(const float* __restrict__ inputs,
                                             const float* __restrict__ Wc,
                                             const float* __restrict__ bc,
                                             int8_t* __restrict__ enc8) {
  const int ht = blockIdx.x;
  const int b  = blockIdx.y;
  const int tid = threadIdx.x;
  const int ts = tid & 63, th = tid >> 6;
  __shared__ float Xs[32 * 260];
  __shared__ float Ws[32 * 64];
  float acc[16][4];
#pragma unroll
  for (int i = 0; i < 16; ++i)
#pragma unroll
    for (int j = 0; j < 4; ++j) acc[i][j] = 0.f;

  const float* Arow = inputs + ((size_t)b * SS + tid) * HH;
  for (int kk = 0; kk < HH; kk += 32) {
    const float4* ip = (const float4*)(Arow + kk);
#pragma unroll
    for (int e = 0; e < 8; ++e) {
      float4 w = ip[e];
      Xs[(e * 4 + 0) * 260 + tid] = w.x;
      Xs[(e * 4 + 1) * 260 + tid] = w.y;
      Xs[(e * 4 + 2) * 260 + tid] = w.z;
      Xs[(e * 4 + 3) * 260 + tid] = w.w;
    }
    {
      int kw = tid >> 3, hw = (tid & 7) * 8;
      const float4* wp = (const float4*)(Wc + (size_t)(kk + kw) * HH + ht * 64 + hw);
      float4 w0 = wp[0], w1 = wp[1];
      float* d = Ws + kw * 64 + hw;
      ((float4*)d)[0] = w0; ((float4*)d)[1] = w1;
    }
    __syncthreads();
#pragma unroll 8
    for (int k = 0; k < 32; ++k) {
      float xr[4];
#pragma unroll
      for (int j = 0; j < 4; ++j) xr[j] = Xs[k * 260 + ts + 64 * j];
      const float4* wr4 = (const float4*)(Ws + k * 64 + th * 16);
#pragma unroll
      for (int i4 = 0; i4 < 4; ++i4) {
        float4 w = wr4[i4];
        float wv[4] = {w.x, w.y, w.z, w.w};
#pragma unroll
        for (int c = 0; c < 4; ++c)
#pragma unroll
          for (int j = 0; j < 4; ++j) acc[i4 * 4 + c][j] += wv[c] * xr[j];
      }
    }
    __syncthreads();
  }
#pragma unroll
  for (int i = 0; i < 16; ++i) {
    int h = ht * 64 + th * 16 + i;
    float bcv = bc[h];
    int8_t* orow = enc8 + (size_t)b * (HH * SS) + (size_t)h * SS + ts;
#pragma unroll
    for (int j = 0; j < 4; ++j) {
      float q = rintf(fminf(fmaxf((acc[i][j] + bcv) * ENC_SCALE, -127.f), 127.f));
      orow[64 * j] = (int8_t)(int)q;
    }
  }
}

// ---------------- Phase A2: G[b][j][k][q] = half( inputs[b,j,:] @ Wq[k] ) ----------------
__global__ __launch_bounds__(256) void k_G(const float* __restrict__ inputs,
                                           const float* __restrict__ Wq,
                                           __half* __restrict__ G) {
  const int qt = blockIdx.x;
  const int b  = blockIdx.y;
  const int k  = blockIdx.z;
  const int tid = threadIdx.x;
  const int ql = tid & 63, tj = tid >> 6;
  __shared__ float Xs[32 * 260];
  __shared__ float Ws[32 * 64];
  float acc[64];
#pragma unroll
  for (int j = 0; j < 64; ++j) acc[j] = 0.f;
  const int q = qt * 64 + ql;
  const float* Arow = inputs + ((size_t)b * SS + tid) * HH;
  const float* Wqk = Wq + (size_t)k * HH * QQ;
  for (int kk = 0; kk < HH; kk += 32) {
    const float4* ip = (const float4*)(Arow + kk);
#pragma unroll
    for (int e = 0; e < 8; ++e) {
      float4 w = ip[e];
      Xs[(e * 4 + 0) * 260 + tid] = w.x;
      Xs[(e * 4 + 1) * 260 + tid] = w.y;
      Xs[(e * 4 + 2) * 260 + tid] = w.z;
      Xs[(e * 4 + 3) * 260 + tid] = w.w;
    }
    {
      int hh = tid >> 3, qw = (tid & 7) * 8;
      const float* src = Wqk + (size_t)(kk + hh) * QQ;
      float* d = Ws + hh * 64 + qw;
#pragma unroll
      for (int e = 0; e < 8; ++e) {
        int qg = qt * 64 + qw + e;
        d[e] = (qg < QQ) ? src[qg] : 0.f;
      }
    }
    __syncthreads();
#pragma unroll 4
    for (int k2 = 0; k2 < 32; ++k2) {
      float wr = Ws[k2 * 64 + ql];
      const float4* xp = (const float4*)(Xs + k2 * 260 + tj * 64);
#pragma unroll
      for (int j4 = 0; j4 < 16; ++j4) {
        float4 x = xp[j4];
        acc[j4 * 4 + 0] += wr * x.x;
        acc[j4 * 4 + 1] += wr * x.y;
        acc[j4 * 4 + 2] += wr * x.z;
        acc[j4 * 4 + 3] += wr * x.w;
      }
    }
    __syncthreads();
  }
  if (q < QQ) {
#pragma unroll
    for (int j = 0; j < 64; ++j) {
      size_t jg = (size_t)b * SS + (tj * 64 + j);
      G[(jg * 3 + k) * QQ + q] = __float2half(acc[j]);
    }
  }
}

// ---------------- W2 pack: W2[qp][h] = half2(w_q[2qp][h], w_q[2qp+1][h]), qp<192 ----------------
__global__ __launch_bounds__(1024) void k_w2(const float* __restrict__ w_q,
                                             __half2* __restrict__ W2) {
  int t = blockIdx.x * 1024 + threadIdx.x;
  if (t < QP2 * HH) {
    int qp = t / HH, h = t % HH;
    float a = (2 * qp < QQ) ? w_q[(size_t)(2 * qp) * HH + h] : 0.f;
    float b = (2 * qp + 1 < QQ) ? w_q[(size_t)(2 * qp + 1) * HH + h] : 0.f;
    W2[t] = __floats2half2_rn(a, b);
  }
}

// ---------------- Main scan: 2 blocks per batch (h-split), tagged exchange ----------------
// Round-13 change: flag handshake (2 barriers + tid0-serial poll) replaced by
// DISTRIBUTED TAGGED slots: {tag=t+1, value} packed in one 8B atomic word.
// 8B atomicity makes tag+value consistent => no flag, no fence, no barrier.
// Each thread polls its own peer slot right where the value is consumed;
// threefry/gumbel computed between publish and poll as latency cover.
// Back to 3 barriers/step. Lap safety: slots double-buffered by t&1 and the
// peer can't be 2 steps ahead (its t+1 poll needs our t publish).
__global__ __launch_bounds__(1024, 4) void k_scan(
    const __half2* __restrict__ W2, const float* __restrict__ v,
    const int8_t* __restrict__ enc8, const __half* __restrict__ G,
    uint64_t* __restrict__ xm,
    float* __restrict__ out, double* __restrict__ lpb, double* __restrict__ entb) {
  const int bid = blockIdx.x;
  const int b = bid & 127;
  const int half = bid >> 7;
  const int tid = (int)threadIdx.x;
  const int lane = tid & 63;
  const int wid = tid >> 6;            // 16 waves
  // P2 geometry: lane = q_sub*4 + hq2; q_sub 0..15 (12 q-pairs each), hq2 0..3 (4 h each)
  const int q_sub = lane >> 2;
  const int hq2 = lane & 3;
  // P3 geometry: wave owns 16 local h; lane-half owns 8 of them
  const int hl = lane >> 5;            // 0..1
  const int sl = lane & 31;
  const int sbase = sl * 8;
  // P4 geometry: 4 threads per s
  const int s4 = tid >> 2;             // 0..255
  const int rq = tid & 3;              // 0..3

  __shared__ uint2 enc_lds[HF * 32];   // 64 KB: own h-slice, uint2[h_loc][sl]
  __shared__ float2 evq[HF];           // .x = CC*eq[h] (per step), .y = -2*v[h]
  __shared__ __half2 q2_s[QP2];        // current query q-pairs (relu'd), pad zeroed
  __shared__ float q12_s[QP];          // prefetched G0+G1 for next step
  __shared__ float part[16][260];
  __shared__ float m_s[SS];
  __shared__ float mask_s[SS];
  __shared__ float4 wred[16];
  __shared__ int hist[3];
  __shared__ float Vtot_s;

  const int hbase = half * HF;

  // ---- init ----
  if (tid < HF) evq[tid] = make_float2(0.f, -2.0f * v[hbase + tid]);
  if (tid < SS) mask_s[tid] = 0.f;
  if (tid < QP) q12_s[tid] = 0.f;
  if (tid < QP2) q2_s[tid] = __floats2half2_rn(0.f, 0.f);
  if (tid < 3) hist[tid] = -1;
  if (tid < 64) {
    float s = 0.f;
#pragma unroll
    for (int j = 0; j < 8; ++j) s += v[tid + 64 * j];   // FULL 512-h sum
#pragma unroll
    for (int off = 32; off; off >>= 1) s += __shfl_xor(s, off);
    if (tid == 0) Vtot_s = s;
  }
  // ---- own enc half -> LDS (64 KB, coalesced) ----
  {
    const uint4* src4 = (const uint4*)(enc8 + (size_t)b * (HH * SS) + (size_t)hbase * SS);
    uint4* dst4 = (uint4*)enc_lds;
#pragma unroll
    for (int it = 0; it < 4; ++it)
      dst4[it * 1024 + tid] = src4[it * 1024 + tid];
  }
  __syncthreads();
  const float Vtot = Vtot_s;

  const __half* Gb = G + (size_t)b * SS * 3 * QQ;
  const __half2* wp2 = W2 + (size_t)(q_sub * 12) * HH + hbase + wid * 16 + hq2 * 4;
  const uint2* encL = enc_lds + (size_t)(wid * 16 + hl) * 32 + sl;
  uint64_t* xm_my = xm + (size_t)(b * 2 + half) * 512;
  const uint64_t* xm_pr = xm + (size_t)(b * 2 + (1 - half)) * 512;

  double lp_acc = 0.0, ent_acc = 0.0;
  int first_idx = 0;

  for (int t = 0; t < SS; ++t) {
    // ---- G prefetch issue (next-step q12) ----
    const int p0 = hist[1], p1 = hist[2];
    uint2 g0raw = make_uint2(0, 0), g1raw = make_uint2(0, 0);
    const bool pf = (tid < 96);
    if (pf) {
      if (p0 >= 0) g0raw = *(const uint2*)(Gb + ((size_t)p0 * 3 + 0) * QQ + 4 * tid);
      if (p1 >= 0) g1raw = *(const uint2*)(Gb + ((size_t)p1 * 3 + 1) * QQ + 4 * tid);
    }

    // ---- P2: eq over own 16-h wave slice; lane: 4 h x 12 q-pairs (fdot2) ----
    {
      float a[4];
#pragma unroll
      for (int j = 0; j < 4; ++j) a[j] = 0.f;
      const __half2* qsp = q2_s + q_sub * 12;
#pragma unroll 4
      for (int i = 0; i < 12; ++i) {
        uint4 raw = *(const uint4*)(wp2 + (size_t)i * HH);   // 4 half2 (4 h, 1 q-pair)
        __half2 qv = qsp[i];
#if __has_builtin(__builtin_amdgcn_fdot2)
        f16x2 qf = *(f16x2*)&qv;
        a[0] = __builtin_amdgcn_fdot2(qf, *(f16x2*)&raw.x, a[0], false);
        a[1] = __builtin_amdgcn_fdot2(qf, *(f16x2*)&raw.y, a[1], false);
        a[2] = __builtin_amdgcn_fdot2(qf, *(f16x2*)&raw.z, a[2], false);
        a[3] = __builtin_amdgcn_fdot2(qf, *(f16x2*)&raw.w, a[3], false);
#else
        float2 qf = __half22float2(qv);
        float2 w0 = __half22float2(*(const __half2*)&raw.x);
        float2 w1 = __half22float2(*(const __half2*)&raw.y);
        float2 w2 = __half22float2(*(const __half2*)&raw.z);
        float2 w3 = __half22float2(*(const __half2*)&raw.w);
        a[0] = fmaf(qf.x, w0.x, fmaf(qf.y, w0.y, a[0]));
        a[1] = fmaf(qf.x, w1.x, fmaf(qf.y, w1.y, a[1]));
        a[2] = fmaf(qf.x, w2.x, fmaf(qf.y, w2.y, a[2]));
        a[3] = fmaf(qf.x, w3.x, fmaf(qf.y, w3.y, a[3]));
#endif
      }
#pragma unroll
      for (int off = 4; off <= 32; off <<= 1)
#pragma unroll
        for (int j = 0; j < 4; ++j) a[j] += __shfl_xor(a[j], off);
      if (lane < 4) {        // q_sub==0, hq2==lane
        int h0 = wid * 16 + lane * 4;
#pragma unroll
        for (int j = 0; j < 4; ++j) evq[h0 + j].x = CC * a[j];
      }
      // no barrier: P3 wave reads only its own wave's evq slice
    }

    // ---- P3: own-half scores (8 h per lane-half, exp2 form) ----
    {
      float acc[8];
#pragma unroll
      for (int j = 0; j < 8; ++j) acc[j] = 0.f;
#pragma unroll
      for (int i = 0; i < 8; ++i) {
        float2 ev = evq[wid * 16 + 2 * i + hl];
        const float eqC = ev.x, mv = ev.y;
        uint2 w = encL[(size_t)(2 * i) * 32];
        const uint32_t w0 = w.x, w1 = w.y;
#pragma unroll
        for (int k = 0; k < 4; ++k) {
          {
            float f = (float)(int)(int8_t)(w0 >> (8 * k));
            float e = EXP2F(fmaf(f, ENC_INV, eqC));
            acc[k] = fmaf(mv, frcp(e + 1.0f), acc[k]);
          }
          {
            float f = (float)(int)(int8_t)(w1 >> (8 * k));
            float e = EXP2F(fmaf(f, ENC_INV, eqC));
            acc[4 + k] = fmaf(mv, frcp(e + 1.0f), acc[4 + k]);
          }
        }
      }
#pragma unroll
      for (int j = 0; j < 8; ++j) acc[j] += __shfl_xor(acc[j], 32);
      if (hl == 0) {
        *(float4*)&part[wid][sbase]     = make_float4(acc[0], acc[1], acc[2], acc[3]);
        *(float4*)&part[wid][sbase + 4] = make_float4(acc[4], acc[5], acc[6], acc[7]);
      }
    }

    // ---- consume q12 prefetch ----
    if (pf) {
      float2 f0a = __half22float2(*(const __half2*)&g0raw.x);
      float2 f0b = __half22float2(*(const __half2*)&g0raw.y);
      float2 f1a = __half22float2(*(const __half2*)&g1raw.x);
      float2 f1b = __half22float2(*(const __half2*)&g1raw.y);
      float4 qv;
      qv.x = f0a.x + f1a.x; qv.y = f0a.y + f1a.y;
      qv.z = f0b.x + f1b.x; qv.w = f0b.y + f1b.y;
      *(float4*)&q12_s[4 * tid] = qv;
    }
    __syncthreads();   // b1: part, q12 ready

    // ---- local reduce (own half-sum per s) + tagged publish ----
    float own;
    {
      own  = part[rq * 4 + 0][s4];
      own += part[rq * 4 + 1][s4];
      own += part[rq * 4 + 2][s4];
      own += part[rq * 4 + 3][s4];
      own += __shfl_xor(own, 1);
      own += __shfl_xor(own, 2);       // all 4 rq lanes: full 16-row sum
      if (rq == 0) {
        uint64_t pk = ((uint64_t)__float_as_uint(own) << 32) | (uint32_t)(t + 1);
        __hip_atomic_store(&xm_my[(t & 1) * 256 + s4], pk,
                           __ATOMIC_RELAXED, __HIP_MEMORY_SCOPE_AGENT);
      }
    }

    // ---- gumbel + mask (latency cover for the peer publish) ----
    float gum, maskv;
    {
      TF2 o = threefry(c_keys.sk[t][0], c_keys.sk[t][1], 0u, (uint32_t)(b * SS + s4));
      float fb = __uint_as_float((o.b >> 9) | 0x3f800000u) - 1.0f;
      fb = fmaxf(fb, 1.0e-12f);
      gum = -__logf(-__logf(fb));
      maskv = mask_s[s4];
    }

    // ================== sampling (redundant in both halves) ==================
    {
      // per-thread poll on own peer slot (tag==t+1 guarantees value validity)
      uint64_t pv = __hip_atomic_load(&xm_pr[(t & 1) * 256 + s4],
                                      __ATOMIC_RELAXED, __HIP_MEMORY_SCOPE_AGENT);
      while ((uint32_t)pv != (uint32_t)(t + 1)) {
        __builtin_amdgcn_s_sleep(1);
        pv = __hip_atomic_load(&xm_pr[(t & 1) * 256 + s4],
                               __ATOMIC_RELAXED, __HIP_MEMORY_SCOPE_AGENT);
      }
      float peer = __uint_as_float((uint32_t)(pv >> 32));
      float sc = Vtot + (own + peer);   // commutative: bitwise-identical both halves
      float logit = 10.0f * fast_tanh(sc);
      float m = (maskv != 0.f) ? -1.0e8f : logit;
      if (rq == 0) m_s[s4] = m;
      float z = m + gum;
      float e = __expf(m);              // masked -> exactly 0
      float em = e * m;
      int si = s4;
#pragma unroll
      for (int off = 4; off <= 32; off <<= 1) {
        float zo = __shfl_xor(z, off);
        int io = __shfl_xor(si, off);
        if (zo > z || (zo == z && io < si)) { z = zo; si = io; }
        e += __shfl_xor(e, off);
        em += __shfl_xor(em, off);
      }
      if (lane == 0) wred[wid] = make_float4(z, __int_as_float(si), e, em);
    }
    __syncthreads();   // b3: wred, m_s ready

    // ================== finalize (all threads) + next-q build ==================
    {
      float4 r0 = wred[0];
      float z = r0.x; int si = __float_as_int(r0.y);
      float se = r0.z, sem = r0.w;
#pragma unroll
      for (int r = 1; r < 16; ++r) {
        float4 rv = wred[r];
        int io = __float_as_int(rv.y);
        if (rv.x > z || (rv.x == z && io < si)) { z = rv.x; si = io; }
        se += rv.z; sem += rv.w;
      }
      const int idx = si;
      if (tid < 90) {   // q = relu(q12 + G2[idx]) -> q2_s half2 pairs
        uint2 g2 = *(const uint2*)(Gb + ((size_t)idx * 3 + 2) * QQ + 4 * tid);
        float2 f2a = __half22float2(*(const __half2*)&g2.x);
        float2 f2b = __half22float2(*(const __half2*)&g2.y);
        float4 q12v = *(const float4*)&q12_s[4 * tid];
        float4 qn;
        qn.x = fmaxf(q12v.x + f2a.x, 0.f);
        qn.y = fmaxf(q12v.y + f2a.y, 0.f);
        qn.z = fmaxf(q12v.z + f2b.x, 0.f);
        qn.w = fmaxf(q12v.w + f2b.y, 0.f);
        q2_s[2 * tid]     = __floats2half2_rn(qn.x, qn.y);
        q2_s[2 * tid + 1] = __floats2half2_rn(qn.z, qn.w);
      }
      if (tid == 0) {
        float lse = __logf(se);
        float mi = m_s[idx];
        lp_acc += (double)(mi - lse);
        ent_acc += (double)(lse - sem / se);
        if (half == 0) out[b * 257 + t] = (float)idx;
        mask_s[idx] = 1.0f;
        hist[0] = hist[1]; hist[1] = hist[2]; hist[2] = idx;
        if (t == 0) first_idx = idx;
      }
    }
    __syncthreads();   // b4: q2_s, hist, mask updated
  }

  if (tid == 0 && half == 0) {
    out[b * 257 + 256] = (float)first_idx;
    lpb[b] = lp_acc;
    entb[b] = ent_acc;
  }
}

// ---------------- Final deterministic reduction ----------------
__global__ void k_final(const double* __restrict__ lpb,
                        const double* __restrict__ entb, float* __restrict__ out) {
  if (threadIdx.x == 0) {
    double a = 0.0, c = 0.0;
    for (int i = 0; i < BB; ++i) { a += lpb[i]; c += entb[i]; }
    out[BB * 257 + 0] = (float)a;
    out[BB * 257 + 1] = (float)c;
  }
}

extern "C" void kernel_launch(void* const* d_in, const int* in_sizes, int n_in,
                              void* d_out, int out_size, void* d_ws, size_t ws_size,
                              hipStream_t stream) {
  const float* inputs = (const float*)d_in[0];
  const float* Wc  = (const float*)d_in[1];
  const float* bc  = (const float*)d_in[2];
  const float* Wq  = (const float*)d_in[3];
  const float* w_q = (const float*)d_in[4];
  const float* v   = (const float*)d_in[5];
  float* out = (float*)d_out;

  char* ws = (char*)d_ws;
  const size_t encBytes = (size_t)BB * HH * SS;            // 16.8 MB int8
  const size_t gBytes   = (size_t)3 * BB * SS * QQ * 2;    // 70.8 MB fp16
  const size_t w2Bytes  = (size_t)QP2 * HH * 4;            // 384 KB half2
  int8_t* enc8 = (int8_t*)ws;
  __half* G   = (__half*)(ws + encBytes);
  __half2* W2 = (__half2*)(ws + encBytes + gBytes);
  size_t xoff = (encBytes + gBytes + w2Bytes + 1023) & ~(size_t)1023;
  uint64_t* xm = (uint64_t*)(ws + xoff);                    // 256 halves * 512 slots * 8B = 1 MB
  double* lpb = (double*)(ws + xoff + 1024 * 1024);
  double* entb = lpb + BB;

  dim3 gA1(8, BB);
  k_enc<<<gA1, 256, 0, stream>>>(inputs, Wc, bc, enc8);
  dim3 gA2(6, BB, 3);
  k_G<<<gA2, 256, 0, stream>>>(inputs, Wq, G);
  k_w2<<<(QP2 * HH + 1023) / 1024, 1024, 0, stream>>>(w_q, W2);
  hipMemsetAsync(xm, 0, 1024 * 1024, stream);

  void* args[] = {(void*)&W2, (void*)&v, (void*)&enc8, (void*)&G,
                  (void*)&xm, (void*)&out, (void*)&lpb, (void*)&entb};
  hipError_t ce = hipLaunchCooperativeKernel((const void*)k_scan, dim3(256), dim3(1024),
                                             args, 0, stream);
  if (ce != hipSuccess) {
    // 256 blocks x 1024 thr x ~89 KB LDS = exactly 1 block/CU on 256 CUs:
    // all blocks co-resident under a regular launch as well.
    k_scan<<<256, 1024, 0, stream>>>(W2, v, enc8, G, xm, out, lpb, entb);
  }
  k_final<<<1, 64, 0, stream>>>(lpb, entb, out);
}